// Round 17
// baseline (264.809 us; speedup 1.0000x reference)
//
#include <hip/hip_runtime.h>

#define CDIM 512
#define TDIM 2048
#define KCODE 1024
#define NTOT 16
#define FH_ELEMS (NTOT * CDIM * TDIM)   // 16777216
#define M_TOTAL 61440                   // 16*(2048+1024+512+256)

typedef unsigned long long u64;
typedef unsigned int u32;
typedef __attribute__((ext_vector_type(8))) short s16x8;
typedef __attribute__((ext_vector_type(4))) float f32x4;
typedef __attribute__((ext_vector_type(4))) int i32x4;
typedef __attribute__((ext_vector_type(2))) int i32x2;

__device__ __forceinline__ u64 umin64(u64 a, u64 b) { return a < b ? a : b; }

// round-to-nearest-even fp32 -> bf16 bits
__device__ __forceinline__ u32 bf16_rne(float f) {
  u32 u = __float_as_uint(f);
  return (u + 0x7fffu + ((u >> 16) & 1u)) >> 16;
}
// pack two consecutive channels into one u32 (low16 = even channel)
__device__ __forceinline__ u32 pack2ch(float v0, float v1) {
  return bf16_rne(v0) | (bf16_rne(v1) << 16);
}
// unpack bf16 pair
__device__ __forceinline__ float bflo(u32 u) { return __uint_as_float(u << 16); }
__device__ __forceinline__ float bfhi(u32 u) {
  return __uint_as_float(u & 0xffff0000u);
}
// byte offset of (m_local row, kbyte) inside a 16KB tile, XOR-swizzled
__device__ __forceinline__ int tile_addr(int ml, int kbyte) {
  return (ml * 128 + kbyte) ^ ((ml & 7) << 4);
}
__device__ __forceinline__ int iclamp(int v, int lo, int hi) {
  return v < lo ? lo : (v > hi ? hi : v);
}

// ---------------------------------------------------------------------------
// prep (merged): blocks [0,256)   = codebook bf16 pack (tiled, XOR-swizzled)
//                blocks [256,512) = csq (one wave per code) + packed 0xFF init
//                blocks [512,1536)= A1 pack of x (16 ch x 4 t per thread)
__global__ __launch_bounds__(256) void prep_kernel(
    const float* __restrict__ cb, char* __restrict__ cb_pack,
    float* __restrict__ csq, const float* __restrict__ x,
    char* __restrict__ a1, u64* __restrict__ packed) {
  const int tid = threadIdx.x;
  const int b = blockIdx.x;
  if (b < 256) {
    const int g = b * 256 + tid;  // 65536 threads x 16B = 1MB
    const int tile = g >> 10;
    const int L = (g & 1023) * 16;
    const int nt = tile >> 3, kc = tile & 7;
    const int code_local = L >> 7;
    const int kbyte = (L & 127) ^ ((code_local & 7) << 4);
    const int code = nt * 128 + code_local;
    const int c0 = kc * 64 + (kbyte >> 1);
    f32x4 va = *(const f32x4*)(cb + (size_t)code * CDIM + c0);
    f32x4 vb = *(const f32x4*)(cb + (size_t)code * CDIM + c0 + 4);
    i32x4 o = {(int)pack2ch(va[0], va[1]), (int)pack2ch(va[2], va[3]),
               (int)pack2ch(vb[0], vb[1]), (int)pack2ch(vb[2], vb[3])};
    *(i32x4*)(cb_pack + (size_t)g * 16) = o;
  } else if (b < 512) {
    const int bb = b - 256;
    if (bb < 240) packed[bb * 256 + tid] = ~0ull;  // exact cover of 61440
    const int code = bb * 4 + (tid >> 6);
    const int t = tid & 63;
    const float* row = cb + (size_t)code * CDIM;
    float s = 0.f;
#pragma unroll
    for (int q = 0; q < 2; ++q) {
      float4 v = *(const float4*)(row + (t * 2 + q) * 4);
      s += v.x * v.x + v.y * v.y + v.z * v.z + v.w * v.w;
    }
#pragma unroll
    for (int off = 32; off; off >>= 1) s += __shfl_down(s, off, 64);
    if (t == 0) csq[code] = s;
  } else {
    const int blk = b - 512;  // [n:16][kc:8][tb:8]
    const int lane = tid & 63, cq = tid >> 6;
    const int tb = blk & 7;
    const int kc = (blk >> 3) & 7;
    const int n = blk >> 6;
    const int c0 = kc * 64 + cq * 16;
    const int t0 = tb * 256 + lane * 4;
    const float* xp = x + (size_t)n * (CDIM * TDIM) + (size_t)c0 * TDIM + t0;
    u32 pk[4][8];
#pragma unroll
    for (int jp = 0; jp < 8; ++jp) {
      f32x4 v0 = *(const f32x4*)(xp + (size_t)(2 * jp) * TDIM);
      f32x4 v1 = *(const f32x4*)(xp + (size_t)(2 * jp + 1) * TDIM);
#pragma unroll
      for (int tt = 0; tt < 4; ++tt) pk[tt][jp] = pack2ch(v0[tt], v1[tt]);
    }
    const int kbyte = cq * 32;
#pragma unroll
    for (int tt = 0; tt < 4; ++tt) {
      const int m = n * TDIM + t0 + tt;
      const size_t tbase = ((size_t)((m >> 7) * 8 + kc)) << 14;
      i32x4 o1 = {(int)pk[tt][0], (int)pk[tt][1], (int)pk[tt][2],
                  (int)pk[tt][3]};
      i32x4 o2 = {(int)pk[tt][4], (int)pk[tt][5], (int)pk[tt][6],
                  (int)pk[tt][7]};
      *(i32x4*)(a1 + tbase + tile_addr(m & 127, kbyte)) = o1;
      *(i32x4*)(a1 + tbase + tile_addr(m & 127, kbyte + 16)) = o2;
    }
  }
}

// ---------------------------------------------------------------------------
// 256x256 MFMA distance GEMM + argmin, 2-phase double-buffered LDS, single
// barrier per K-step (stage-early). 8 waves = 2(code) x 4(m). grid = nx*4,
// XCD-chunked so the 4 code-tiles of one m-tile share an XCD L2.
// LDS buffer layout: [0:32K) = x rows (m), [32K:64K) = codebook rows.
__global__ __launch_bounds__(512, 2) void gemm_argmin_packed(
    const char* __restrict__ a_pack,   // [m_tiles(128r)][8][16KB]
    const char* __restrict__ cb_pack,  // [8][8][16KB]
    const float* __restrict__ csq,
    u64* __restrict__ packed) {
  __shared__ __align__(16) char smem[131072 + 1024];
  float* csq_s = (float*)(smem + 131072);

  const int id = blockIdx.x;
  const int nxq = gridDim.x >> 5;  // nx/8   (gridDim.x = nx*4)
  const int xcd = id & 7;
  const int rr = id >> 3;
  const int bx = xcd * nxq + (rr >> 2);
  const int by = rr & 3;

  const int tid = threadIdx.x;
  const int lane = tid & 63;
  const int w = tid >> 6;   // 0..7
  const int wc = w >> 2;    // code half (0..1)
  const int wm = w & 3;     // m quarter (0..3)
  const int row_base = bx * 256;
  const int code_base = by * 256;
  if (tid < 256) csq_s[tid] = csq[code_base + tid];

  const f32x4 zero = {0.f, 0.f, 0.f, 0.f};
  f32x4 acc[8][4];
#pragma unroll
  for (int fc = 0; fc < 8; ++fc)
#pragma unroll
    for (int fm = 0; fm < 4; ++fm) acc[fc][fm] = zero;

  const size_t aBase = ((size_t)(bx * 2) * 8) << 14;
  const size_t bBase = ((size_t)(by * 2) * 8) << 14;

  auto stage = [&](int buf, int kc) {
    char* dst = smem + buf * 65536;
    const char* gA0 = a_pack + aBase + ((size_t)kc << 14);
    const char* gA1 = a_pack + aBase + ((size_t)(8 + kc) << 14);
    const char* gB0 = cb_pack + bBase + ((size_t)kc << 14);
    const char* gB1 = cb_pack + bBase + ((size_t)(8 + kc) << 14);
    const int o = tid * 16;
#pragma unroll
    for (int p = 0; p < 2; ++p) {
      const int q = o + p * 8192;
      __builtin_amdgcn_global_load_lds(
          (const __attribute__((address_space(1))) u32*)(gA0 + q),
          (__attribute__((address_space(3))) u32*)(dst + q), 16, 0, 0);
      __builtin_amdgcn_global_load_lds(
          (const __attribute__((address_space(1))) u32*)(gA1 + q),
          (__attribute__((address_space(3))) u32*)(dst + 16384 + q), 16, 0, 0);
      __builtin_amdgcn_global_load_lds(
          (const __attribute__((address_space(1))) u32*)(gB0 + q),
          (__attribute__((address_space(3))) u32*)(dst + 32768 + q), 16, 0, 0);
      __builtin_amdgcn_global_load_lds(
          (const __attribute__((address_space(1))) u32*)(gB1 + q),
          (__attribute__((address_space(3))) u32*)(dst + 49152 + q), 16, 0, 0);
    }
  };

  stage(0, 0);
  __syncthreads();

  int cur = 0;
  for (int kc = 0; kc < 8; ++kc) {
    if (kc < 7) stage(cur ^ 1, kc + 1);  // loads in flight across compute
    const char* X = smem + cur * 65536;  // x rows (m dimension)
    const char* C = X + 32768;           // codebook rows
#pragma unroll
    for (int ks = 0; ks < 2; ++ks) {
      const int kb = ks * 64 + (lane >> 4) * 16;
      s16x8 af[8], bq[4];
#pragma unroll
      for (int fc = 0; fc < 8; ++fc) {
        const int cr = wc * 128 + fc * 16 + (lane & 15);
        af[fc] = *(const s16x8*)(C + ((cr >> 7) << 14) +
                                 tile_addr(cr & 127, kb));
      }
#pragma unroll
      for (int fm = 0; fm < 4; ++fm) {
        const int mr = wm * 64 + fm * 16 + (lane & 15);
        bq[fm] = *(const s16x8*)(X + ((mr >> 7) << 14) +
                                 tile_addr(mr & 127, kb));
      }
      __builtin_amdgcn_s_setprio(1);
#pragma unroll
      for (int fc = 0; fc < 8; ++fc)
#pragma unroll
        for (int fm = 0; fm < 4; ++fm)
          acc[fc][fm] = __builtin_amdgcn_mfma_f32_16x16x32_bf16(
              af[fc], bq[fm], acc[fc][fm], 0, 0, 0);
      __builtin_amdgcn_s_setprio(0);
    }
    __syncthreads();  // drains stage loads + all waves' LDS reads
    cur ^= 1;
  }

  u64 best[4] = {~0ull, ~0ull, ~0ull, ~0ull};
#pragma unroll
  for (int fc = 0; fc < 8; ++fc) {
#pragma unroll
    for (int r4 = 0; r4 < 4; ++r4) {
      const int cl = wc * 128 + fc * 16 + (lane >> 4) * 4 + r4;
      const float cs = csq_s[cl];
      const u64 codebits = (u32)(code_base + cl);
#pragma unroll
      for (int fm = 0; fm < 4; ++fm) {
        float d = fmaf(-2.0f, acc[fc][fm][r4], cs);
        u32 u = __float_as_uint(d);
        u = (u & 0x80000000u) ? ~u : (u | 0x80000000u);
        best[fm] = umin64(best[fm], ((u64)u << 32) | codebits);
      }
    }
  }
#pragma unroll
  for (int fm = 0; fm < 4; ++fm) {
    u64 b = best[fm];
#pragma unroll
    for (int off = 16; off < 64; off <<= 1) {
      u32 lo = (u32)b, hi = (u32)(b >> 32);
      lo = (u32)__shfl_xor((int)lo, off, 64);
      hi = (u32)__shfl_xor((int)hi, off, 64);
      b = umin64(b, ((u64)hi << 32) | lo);
    }
    if ((lane >> 4) == 0)
      atomicMin(&packed[row_base + wm * 64 + fm * 16 + (lane & 15)], b);
  }
}

// ---------------------------------------------------------------------------
// pack2: A2 = pool2(x - up1) bf16 + poolb2 (packed bf16, [n][tau][256 u32]).
__global__ __launch_bounds__(256) void pack2_kernel(
    const float* __restrict__ x, const float* __restrict__ cb,
    const u64* __restrict__ packed, char* __restrict__ a2,
    u32* __restrict__ poolb2) {
  __shared__ float rows1[16][516];
  __shared__ int idx1[16];
  const int tid = threadIdx.x;
  const int blk = blockIdx.x;  // 16 n x 128 tiles
  const int n = blk >> 7;
  const int tau0 = (blk & 127) * 8;
  const int tb = tau0 * 2;  // full-res t in [tb, tb+16)
  if (tid < 16)
    idx1[tid] = (int)(packed[(size_t)n * TDIM + tb + tid] & 0xffffffffull);
  __syncthreads();
  {
    const int rj = tid >> 4, c16 = tid & 15;
    const float* src = cb + (size_t)idx1[rj] * CDIM;
#pragma unroll
    for (int q = 0; q < 8; ++q) {
      const int c = c16 * 4 + q * 64;
      *(f32x4*)&rows1[rj][c] = *(const f32x4*)(src + c);
    }
  }
  __syncthreads();

  const int cg = tid >> 1, half = tid & 1;
  const int c0 = cg * 4;
  const int tl0 = half * 8;  // local t base
  const size_t xbase =
      (size_t)n * (CDIM * TDIM) + (size_t)c0 * TDIM + tb + tl0;

  f32x4 ru[8];
#pragma unroll
  for (int t = 0; t < 8; ++t) ru[t] = *(const f32x4*)&rows1[tl0 + t][c0];

  float p2[4][4];  // [c][q]
#pragma unroll
  for (int j = 0; j < 4; ++j) {
    f32x4 xa = *(const f32x4*)(x + xbase + (size_t)j * TDIM);
    f32x4 xb = *(const f32x4*)(x + xbase + (size_t)j * TDIM + 4);
#pragma unroll
    for (int q = 0; q < 4; ++q) {
      const float e0 = (q < 2) ? xa[2 * q] : xb[2 * q - 4];
      const float e1 = (q < 2) ? xa[2 * q + 1] : xb[2 * q - 3];
      const float r0 = e0 - ru[2 * q][j];
      const float r1 = e1 - ru[2 * q + 1][j];
      p2[j][q] = (r0 + r1) * 0.5f;
    }
  }
  const int kc = c0 >> 6, kbyte = (c0 & 63) * 2;
#pragma unroll
  for (int q = 0; q < 4; ++q) {
    const int tau = tau0 + half * 4 + q;
    i32x2 o = {(int)pack2ch(p2[0][q], p2[1][q]),
               (int)pack2ch(p2[2][q], p2[3][q])};
    // poolb2 (same bits)
    *(i32x2*)(poolb2 + (size_t)n * (1024 * 256) + (size_t)tau * 256 +
              (c0 >> 1)) = o;
    // a2 tile
    const int m = n * 1024 + tau;
    *(i32x2*)(a2 + (((size_t)((m >> 7) * 8 + kc)) << 14) +
              tile_addr(m & 127, kbyte)) = o;
  }
}

// ---------------------------------------------------------------------------
// packN: pool chain at coarse res; pin/pout are packed-bf16 [n][T*][256 u32].
template <int TP, bool WPOOL>
__global__ __launch_bounds__(256) void packN_kernel(
    const u32* __restrict__ pin, const float* __restrict__ cb,
    const u64* __restrict__ packed, char* __restrict__ a_next,
    u32* __restrict__ pout) {
  constexpr int OFF = (TP == 1024) ? 32768 : 49152;  // scale-2 / scale-4 idx
  constexpr int TILES = TP / 16;
  constexpr int TO = TP / 2;
  __shared__ float rows[18][516];
  __shared__ int idxs[18];
  const int tid = threadIdx.x;
  const int blk = blockIdx.x;  // 16 n x TILES
  const int n = blk / TILES;
  const int o0 = (blk % TILES) * 8;  // output tau base
  const int s0 = o0 * 2;             // input sigma base
  if (tid < 18) {
    const int sig = iclamp(s0 - 1 + tid, 0, TP - 1);
    idxs[tid] = (int)(packed[OFF + (size_t)n * TP + sig] & 0xffffffffull);
  }
  __syncthreads();
  for (int j = 0; j < 18; ++j) {
    const int c = tid * 2;
    const float* src = cb + (size_t)idxs[j] * CDIM + c;
    rows[j][c] = src[0];
    rows[j][c + 1] = src[1];
  }
  __syncthreads();

  const int cg = tid >> 1, half = tid & 1;
  const int c0 = cg * 4;
  f32x4 inv[8];
#pragma unroll
  for (int l = 0; l < 8; ++l) {
    i32x2 v = *(const i32x2*)(pin + (size_t)n * (TP * 256) +
                              (size_t)(s0 + half * 8 + l) * 256 + (c0 >> 1));
    inv[l][0] = bflo((u32)v[0]);
    inv[l][1] = bfhi((u32)v[0]);
    inv[l][2] = bflo((u32)v[1]);
    inv[l][3] = bfhi((u32)v[1]);
  }

  float pv[4][4];
#pragma unroll
  for (int q = 0; q < 4; ++q) {
    const int e = half * 8 + 2 * q;
    const int sa = e + 1, sb = e + 2;
    f32x4 Rm = *(const f32x4*)&rows[sa - 1][c0];
    f32x4 Rc = *(const f32x4*)&rows[sa][c0];
    f32x4 Rp = *(const f32x4*)&rows[sb][c0];
    f32x4 Rpp = *(const f32x4*)&rows[sb + 1][c0];
    f32x4 ua = 0.125f * (Rm + Rp) + 0.75f * Rc;
    f32x4 ub = 0.125f * (Rc + Rpp) + 0.75f * Rp;
#pragma unroll
    for (int j = 0; j < 4; ++j)
      pv[j][q] = ((inv[2 * q][j] - ua[j]) + (inv[2 * q + 1][j] - ub[j])) * 0.5f;
  }

  const int kc = c0 >> 6, kbyte = (c0 & 63) * 2;
#pragma unroll
  for (int q = 0; q < 4; ++q) {
    const int tau = o0 + half * 4 + q;
    i32x2 o = {(int)pack2ch(pv[0][q], pv[1][q]),
               (int)pack2ch(pv[2][q], pv[3][q])};
    if constexpr (WPOOL) {
      *(i32x2*)(pout + (size_t)n * (TO * 256) + (size_t)tau * 256 +
                (c0 >> 1)) = o;
    }
    const int m = n * TO + tau;
    *(i32x2*)(a_next + (((size_t)((m >> 7) * 8 + kc)) << 14) +
              tile_addr(m & 127, kbyte)) = o;
  }
}

// ---------------------------------------------------------------------------
// final: full-res pass: 4 per-stage losses + f_hat. No LDS staging; each
// thread processes TWO independent t-quads (2x MLP). Grid 2048.
__global__ __launch_bounds__(256) void final_kernel(
    const float* __restrict__ x, float* __restrict__ out,
    const float* __restrict__ cb, const u64* __restrict__ packed,
    float* __restrict__ lossPart) {
  const int tid = threadIdx.x;
  const int blk = blockIdx.x;  // [n:16][t32:64][ch:2]
  const int ch = blk & 1;
  const int t0 = ((blk >> 1) & 63) * 32;
  const int n = blk >> 7;
  const int cg = tid >> 2, qt = tid & 3;
  const int c0 = ch * 256 + cg * 4;
  const int tbA = t0 + qt * 4;
  const int tbB = t0 + 16 + qt * 4;

  const u64* ip1 = packed + (size_t)n * TDIM;
  const u64* ip2 = packed + 32768 + (size_t)n * 1024;
  const u64* ip4 = packed + 49152 + (size_t)n * 512;
  const u64* ip8 = packed + 57344 + (size_t)n * 256;

  // --- gather both tiles' code-row windows (interleaved for MLP) ---
  f32x4 R1A[4], R2A[4], R4A[3], R8A[2];
  f32x4 R1B[4], R2B[4], R4B[3], R8B[2];
#pragma unroll
  for (int k = 0; k < 4; ++k) {
    R1A[k] = *(const f32x4*)(
        cb + (size_t)(u32)(ip1[tbA + k] & 0xffffffffull) * CDIM + c0);
    R1B[k] = *(const f32x4*)(
        cb + (size_t)(u32)(ip1[tbB + k] & 0xffffffffull) * CDIM + c0);
  }
  const int b2A = tbA >> 1, b2B = tbB >> 1;
#pragma unroll
  for (int k = 0; k < 4; ++k) {
    R2A[k] = *(const f32x4*)(
        cb + (size_t)(u32)(ip2[iclamp(b2A - 1 + k, 0, 1023)] & 0xffffffffull) *
                 CDIM + c0);
    R2B[k] = *(const f32x4*)(
        cb + (size_t)(u32)(ip2[iclamp(b2B - 1 + k, 0, 1023)] & 0xffffffffull) *
                 CDIM + c0);
  }
  const int b4A = tbA >> 2, b4B = tbB >> 2;
#pragma unroll
  for (int k = 0; k < 3; ++k) {
    R4A[k] = *(const f32x4*)(
        cb + (size_t)(u32)(ip4[iclamp(b4A - 1 + k, 0, 511)] & 0xffffffffull) *
                 CDIM + c0);
    R4B[k] = *(const f32x4*)(
        cb + (size_t)(u32)(ip4[iclamp(b4B - 1 + k, 0, 511)] & 0xffffffffull) *
                 CDIM + c0);
  }
  const int b8A = (tbA >> 3) - 1 + ((tbA >> 2) & 1);
  const int b8B = (tbB >> 3) - 1 + ((tbB >> 2) & 1);
#pragma unroll
  for (int k = 0; k < 2; ++k) {
    R8A[k] = *(const f32x4*)(
        cb + (size_t)(u32)(ip8[iclamp(b8A + k, 0, 255)] & 0xffffffffull) *
                 CDIM + c0);
    R8B[k] = *(const f32x4*)(
        cb + (size_t)(u32)(ip8[iclamp(b8B + k, 0, 255)] & 0xffffffffull) *
                 CDIM + c0);
  }

  const size_t xbaseA = (size_t)n * (CDIM * TDIM) + (size_t)c0 * TDIM + tbA;
  const size_t xbaseB = xbaseA + 16;
  f32x4 xaA[4], xaB[4], faA[4], faB[4];
#pragma unroll
  for (int j = 0; j < 4; ++j) {
    xaA[j] = *(const f32x4*)(x + xbaseA + (size_t)j * TDIM);
    xaB[j] = *(const f32x4*)(x + xbaseB + (size_t)j * TDIM);
  }

  // per-tt slot/weight tables (tb ≡ 0 mod 4)
  const int s2n[4] = {0, 1, 1, 2};
  const float w2n[4] = {0.75f, 0.25f, 0.75f, 0.25f};
  const int s4n[4] = {0, 0, 1, 1};
  const float w4n[4] = {0.625f, 0.875f, 0.125f, 0.375f};
  const float w8bA = (tbA & 4) ? 0.0625f : 0.5625f;
  const float w8bB = (tbB & 4) ? 0.0625f : 0.5625f;

  float ss1 = 0.f, ss2 = 0.f, ss3 = 0.f, ss4 = 0.f;
#pragma unroll
  for (int tt = 0; tt < 4; ++tt) {
    // tile A
    {
      f32x4 u2 = R2A[s2n[tt]] * (1.f - w2n[tt]) + R2A[s2n[tt] + 1] * w2n[tt];
      f32x4 u4 = R4A[s4n[tt]] * (1.f - w4n[tt]) + R4A[s4n[tt] + 1] * w4n[tt];
      const float w8 = w8bA + tt * 0.125f;
      f32x4 u8 = R8A[0] * (1.f - w8) + R8A[1] * w8;
      f32x4 xv;
#pragma unroll
      for (int j = 0; j < 4; ++j) xv[j] = xaA[j][tt];
      f32x4 r1 = xv - R1A[tt];
      f32x4 r2 = r1 - u2;
      f32x4 r3 = r2 - u4;
      f32x4 r4 = r3 - u8;
#pragma unroll
      for (int j = 0; j < 4; ++j) {
        ss1 += r1[j] * r1[j];
        ss2 += r2[j] * r2[j];
        ss3 += r3[j] * r3[j];
        ss4 += r4[j] * r4[j];
      }
      f32x4 fh = xv - r4;
#pragma unroll
      for (int j = 0; j < 4; ++j) faA[j][tt] = fh[j];
    }
    // tile B
    {
      f32x4 u2 = R2B[s2n[tt]] * (1.f - w2n[tt]) + R2B[s2n[tt] + 1] * w2n[tt];
      f32x4 u4 = R4B[s4n[tt]] * (1.f - w4n[tt]) + R4B[s4n[tt] + 1] * w4n[tt];
      const float w8 = w8bB + tt * 0.125f;
      f32x4 u8 = R8B[0] * (1.f - w8) + R8B[1] * w8;
      f32x4 xv;
#pragma unroll
      for (int j = 0; j < 4; ++j) xv[j] = xaB[j][tt];
      f32x4 r1 = xv - R1B[tt];
      f32x4 r2 = r1 - u2;
      f32x4 r3 = r2 - u4;
      f32x4 r4 = r3 - u8;
#pragma unroll
      for (int j = 0; j < 4; ++j) {
        ss1 += r1[j] * r1[j];
        ss2 += r2[j] * r2[j];
        ss3 += r3[j] * r3[j];
        ss4 += r4[j] * r4[j];
      }
      f32x4 fh = xv - r4;
#pragma unroll
      for (int j = 0; j < 4; ++j) faB[j][tt] = fh[j];
    }
  }
#pragma unroll
  for (int j = 0; j < 4; ++j) {
    *(f32x4*)(out + xbaseA + (size_t)j * TDIM) = faA[j];
    *(f32x4*)(out + xbaseB + (size_t)j * TDIM) = faB[j];
  }

  __shared__ float red2[4][4];
  float sv[4] = {ss1, ss2, ss3, ss4};
  const int w = tid >> 6, lane = tid & 63;
#pragma unroll
  for (int st = 0; st < 4; ++st) {
    float v = sv[st];
#pragma unroll
    for (int off = 32; off; off >>= 1) v += __shfl_down(v, off, 64);
    if (lane == 0) red2[w][st] = v;
  }
  __syncthreads();
  if (tid < 4)
    lossPart[tid * 2048 + blk] =
        red2[0][tid] + red2[1][tid] + red2[2][tid] + red2[3][tid];
}

// ---------------------------------------------------------------------------
// finalize: loss sum + full histogram (LDS-local over all 61440) + perplexity.
__global__ __launch_bounds__(256) void finalize_kernel(
    const float* __restrict__ lossPart, const u64* __restrict__ packed,
    float* __restrict__ outTail) {
  __shared__ float red[4];
  __shared__ int lhist[KCODE];
  const int tid = threadIdx.x;
  for (int k = tid; k < KCODE; k += 256) lhist[k] = 0;
  __syncthreads();
  for (int i = tid; i < M_TOTAL; i += 256) {
    const int code = (int)(packed[i] & 0xffffffffull);
    atomicAdd(&lhist[code], 1);
  }
  float s = 0.f;
  for (int i = tid; i < 4 * 2048; i += 256) s += lossPart[i];
#pragma unroll
  for (int off = 32; off; off >>= 1) s += __shfl_down(s, off, 64);
  if ((tid & 63) == 0) red[tid >> 6] = s;
  __syncthreads();
  const float loss =
      (red[0] + red[1] + red[2] + red[3]) * (1.0f / (4.0f * 16777216.0f));
  __syncthreads();
  float e = 0.f;
  for (int k = tid; k < KCODE; k += 256) {
    float p = (float)lhist[k] * (1.0f / 61440.0f);
    e += p * logf(p + 1e-7f);
  }
#pragma unroll
  for (int off = 32; off; off >>= 1) e += __shfl_down(e, off, 64);
  if ((tid & 63) == 0) red[tid >> 6] = e;
  __syncthreads();
  if (tid == 0) {
    outTail[0] = loss;
    outTail[1] = expf(-(red[0] + red[1] + red[2] + red[3]));
  }
}

// ---------------------------------------------------------------------------
extern "C" void kernel_launch(void* const* d_in, const int* in_sizes, int n_in,
                              void* d_out, int out_size, void* d_ws,
                              size_t ws_size, hipStream_t stream) {
  const float* x = (const float*)d_in[0];
  const float* cb = (const float*)d_in[1];
  float* out = (float*)d_out;

  char* ws = (char*)d_ws;
  u64* packed = (u64*)ws;                   // 491520 B
  float* csq = (float*)(ws + 491520);       // 4096 B
  float* lossPart = (float*)(ws + 499712);  // 32768 B (4 x 2048)
  char* cb_pack = ws + 565248;              // 1 MiB
  char* a2 = ws + (2ull << 20);             // 16 MiB
  char* a4 = ws + (18ull << 20);            // 8 MiB
  char* a8 = ws + (26ull << 20);            // 4 MiB

  u64* p1 = packed;          // 32768 rows (t_s=2048)
  u64* p2 = packed + 32768;  // 16384 rows
  u64* p4 = packed + 49152;  //  8192 rows
  u64* p8 = packed + 57344;  //  4096 rows

  // d_out region reuse: A1 (32MB) until gemm1; then poolb2 [0,16MB) +
  // poolb4 [16,24MB) (packed bf16); finally f_hat overwrites everything.
  char* a1 = (char*)out;
  u32* poolb2 = (u32*)out;                  // [n][1024][256 u32] = 16 MB
  u32* poolb4 = (u32*)out + 4194304;        // [n][512][256 u32]  =  8 MB

  prep_kernel<<<1536, 256, 0, stream>>>(cb, cb_pack, csq, x, a1, packed);
  gemm_argmin_packed<<<128 * 4, 512, 0, stream>>>(a1, cb_pack, csq, p1);
  pack2_kernel<<<2048, 256, 0, stream>>>(x, cb, packed, a2, poolb2);
  gemm_argmin_packed<<<64 * 4, 512, 0, stream>>>(a2, cb_pack, csq, p2);
  packN_kernel<1024, true>
      <<<1024, 256, 0, stream>>>(poolb2, cb, packed, a4, poolb4);
  gemm_argmin_packed<<<32 * 4, 512, 0, stream>>>(a4, cb_pack, csq, p4);
  packN_kernel<512, false>
      <<<512, 256, 0, stream>>>(poolb4, cb, packed, a8, nullptr);
  gemm_argmin_packed<<<16 * 4, 512, 0, stream>>>(a8, cb_pack, csq, p8);
  final_kernel<<<2048, 256, 0, stream>>>(x, out, cb, packed, lossPart);
  finalize_kernel<<<1, 256, 0, stream>>>(lossPart, packed, out + FH_ELEMS);
}

// Round 18
// 219.365 us; speedup vs baseline: 1.2072x; 1.2072x over previous
//
#include <hip/hip_runtime.h>

#define CDIM 512
#define TDIM 2048
#define KCODE 1024
#define NTOT 16
#define FH_ELEMS (NTOT * CDIM * TDIM)   // 16777216
#define M_TOTAL 61440                   // 16*(2048+1024+512+256)

typedef unsigned long long u64;
typedef unsigned int u32;
typedef __attribute__((ext_vector_type(8))) short s16x8;
typedef __attribute__((ext_vector_type(4))) float f32x4;
typedef __attribute__((ext_vector_type(4))) int i32x4;
typedef __attribute__((ext_vector_type(2))) int i32x2;

__device__ __forceinline__ u64 umin64(u64 a, u64 b) { return a < b ? a : b; }

// round-to-nearest-even fp32 -> bf16 bits
__device__ __forceinline__ u32 bf16_rne(float f) {
  u32 u = __float_as_uint(f);
  return (u + 0x7fffu + ((u >> 16) & 1u)) >> 16;
}
// pack two consecutive channels into one u32 (low16 = even channel)
__device__ __forceinline__ u32 pack2ch(float v0, float v1) {
  return bf16_rne(v0) | (bf16_rne(v1) << 16);
}
// unpack bf16 pair
__device__ __forceinline__ float bflo(u32 u) { return __uint_as_float(u << 16); }
__device__ __forceinline__ float bfhi(u32 u) {
  return __uint_as_float(u & 0xffff0000u);
}
// byte offset of (m_local row, kbyte) inside a 16KB tile, XOR-swizzled
__device__ __forceinline__ int tile_addr(int ml, int kbyte) {
  return (ml * 128 + kbyte) ^ ((ml & 7) << 4);
}
__device__ __forceinline__ int iclamp(int v, int lo, int hi) {
  return v < lo ? lo : (v > hi ? hi : v);
}

// ---------------------------------------------------------------------------
// prep (merged): blocks [0,256)   = codebook bf16 pack (tiled, XOR-swizzled)
//                blocks [256,512) = csq + packed 0xFF init + hist zeroing
//                blocks [512,1536)= A1 pack of x (16 ch x 4 t per thread)
__global__ __launch_bounds__(256) void prep_kernel(
    const float* __restrict__ cb, char* __restrict__ cb_pack,
    float* __restrict__ csq, const float* __restrict__ x,
    char* __restrict__ a1, u64* __restrict__ packed, int* __restrict__ hist) {
  const int tid = threadIdx.x;
  const int b = blockIdx.x;
  if (b < 256) {
    const int g = b * 256 + tid;  // 65536 threads x 16B = 1MB
    const int tile = g >> 10;
    const int L = (g & 1023) * 16;
    const int nt = tile >> 3, kc = tile & 7;
    const int code_local = L >> 7;
    const int kbyte = (L & 127) ^ ((code_local & 7) << 4);
    const int code = nt * 128 + code_local;
    const int c0 = kc * 64 + (kbyte >> 1);
    f32x4 va = *(const f32x4*)(cb + (size_t)code * CDIM + c0);
    f32x4 vb = *(const f32x4*)(cb + (size_t)code * CDIM + c0 + 4);
    i32x4 o = {(int)pack2ch(va[0], va[1]), (int)pack2ch(va[2], va[3]),
               (int)pack2ch(vb[0], vb[1]), (int)pack2ch(vb[2], vb[3])};
    *(i32x4*)(cb_pack + (size_t)g * 16) = o;
  } else if (b < 512) {
    const int bb = b - 256;
    if (bb < 240) packed[bb * 256 + tid] = ~0ull;  // exact cover of 61440
    if (bb < 4) hist[bb * 256 + tid] = 0;
    const int code = bb * 4 + (tid >> 6);
    const int t = tid & 63;
    const float* row = cb + (size_t)code * CDIM;
    float s = 0.f;
#pragma unroll
    for (int q = 0; q < 2; ++q) {
      float4 v = *(const float4*)(row + (t * 2 + q) * 4);
      s += v.x * v.x + v.y * v.y + v.z * v.z + v.w * v.w;
    }
#pragma unroll
    for (int off = 32; off; off >>= 1) s += __shfl_down(s, off, 64);
    if (t == 0) csq[code] = s;
  } else {
    const int blk = b - 512;  // [n:16][kc:8][tb:8]
    const int lane = tid & 63, cq = tid >> 6;
    const int tb = blk & 7;
    const int kc = (blk >> 3) & 7;
    const int n = blk >> 6;
    const int c0 = kc * 64 + cq * 16;
    const int t0 = tb * 256 + lane * 4;
    const float* xp = x + (size_t)n * (CDIM * TDIM) + (size_t)c0 * TDIM + t0;
    u32 pk[4][8];
#pragma unroll
    for (int jp = 0; jp < 8; ++jp) {
      f32x4 v0 = *(const f32x4*)(xp + (size_t)(2 * jp) * TDIM);
      f32x4 v1 = *(const f32x4*)(xp + (size_t)(2 * jp + 1) * TDIM);
#pragma unroll
      for (int tt = 0; tt < 4; ++tt) pk[tt][jp] = pack2ch(v0[tt], v1[tt]);
    }
    const int kbyte = cq * 32;
#pragma unroll
    for (int tt = 0; tt < 4; ++tt) {
      const int m = n * TDIM + t0 + tt;
      const size_t tbase = ((size_t)((m >> 7) * 8 + kc)) << 14;
      i32x4 o1 = {(int)pk[tt][0], (int)pk[tt][1], (int)pk[tt][2],
                  (int)pk[tt][3]};
      i32x4 o2 = {(int)pk[tt][4], (int)pk[tt][5], (int)pk[tt][6],
                  (int)pk[tt][7]};
      *(i32x4*)(a1 + tbase + tile_addr(m & 127, kbyte)) = o1;
      *(i32x4*)(a1 + tbase + tile_addr(m & 127, kbyte + 16)) = o2;
    }
  }
}

// ---------------------------------------------------------------------------
// 256x256 MFMA distance GEMM + argmin, 2-phase double-buffered LDS, single
// barrier per K-step (stage-early). 8 waves = 2(code) x 4(m). grid = nx*4,
// XCD-chunked so the 4 code-tiles of one m-tile share an XCD L2.
// LDS buffer layout: [0:32K) = x rows (m), [32K:64K) = codebook rows.
__global__ __launch_bounds__(512, 2) void gemm_argmin_packed(
    const char* __restrict__ a_pack,   // [m_tiles(128r)][8][16KB]
    const char* __restrict__ cb_pack,  // [8][8][16KB]
    const float* __restrict__ csq,
    u64* __restrict__ packed) {
  __shared__ __align__(16) char smem[131072 + 1024];
  float* csq_s = (float*)(smem + 131072);

  const int id = blockIdx.x;
  const int nxq = gridDim.x >> 5;  // nx/8   (gridDim.x = nx*4)
  const int xcd = id & 7;
  const int rr = id >> 3;
  const int bx = xcd * nxq + (rr >> 2);
  const int by = rr & 3;

  const int tid = threadIdx.x;
  const int lane = tid & 63;
  const int w = tid >> 6;   // 0..7
  const int wc = w >> 2;    // code half (0..1)
  const int wm = w & 3;     // m quarter (0..3)
  const int row_base = bx * 256;
  const int code_base = by * 256;
  if (tid < 256) csq_s[tid] = csq[code_base + tid];

  const f32x4 zero = {0.f, 0.f, 0.f, 0.f};
  f32x4 acc[8][4];
#pragma unroll
  for (int fc = 0; fc < 8; ++fc)
#pragma unroll
    for (int fm = 0; fm < 4; ++fm) acc[fc][fm] = zero;

  const size_t aBase = ((size_t)(bx * 2) * 8) << 14;
  const size_t bBase = ((size_t)(by * 2) * 8) << 14;

  auto stage = [&](int buf, int kc) {
    char* dst = smem + buf * 65536;
    const char* gA0 = a_pack + aBase + ((size_t)kc << 14);
    const char* gA1 = a_pack + aBase + ((size_t)(8 + kc) << 14);
    const char* gB0 = cb_pack + bBase + ((size_t)kc << 14);
    const char* gB1 = cb_pack + bBase + ((size_t)(8 + kc) << 14);
    const int o = tid * 16;
#pragma unroll
    for (int p = 0; p < 2; ++p) {
      const int q = o + p * 8192;
      __builtin_amdgcn_global_load_lds(
          (const __attribute__((address_space(1))) u32*)(gA0 + q),
          (__attribute__((address_space(3))) u32*)(dst + q), 16, 0, 0);
      __builtin_amdgcn_global_load_lds(
          (const __attribute__((address_space(1))) u32*)(gA1 + q),
          (__attribute__((address_space(3))) u32*)(dst + 16384 + q), 16, 0, 0);
      __builtin_amdgcn_global_load_lds(
          (const __attribute__((address_space(1))) u32*)(gB0 + q),
          (__attribute__((address_space(3))) u32*)(dst + 32768 + q), 16, 0, 0);
      __builtin_amdgcn_global_load_lds(
          (const __attribute__((address_space(1))) u32*)(gB1 + q),
          (__attribute__((address_space(3))) u32*)(dst + 49152 + q), 16, 0, 0);
    }
  };

  stage(0, 0);
  __syncthreads();

  int cur = 0;
  for (int kc = 0; kc < 8; ++kc) {
    if (kc < 7) stage(cur ^ 1, kc + 1);  // loads in flight across compute
    const char* X = smem + cur * 65536;  // x rows (m dimension)
    const char* C = X + 32768;           // codebook rows
#pragma unroll
    for (int ks = 0; ks < 2; ++ks) {
      const int kb = ks * 64 + (lane >> 4) * 16;
      s16x8 af[8], bq[4];
#pragma unroll
      for (int fc = 0; fc < 8; ++fc) {
        const int cr = wc * 128 + fc * 16 + (lane & 15);
        af[fc] = *(const s16x8*)(C + ((cr >> 7) << 14) +
                                 tile_addr(cr & 127, kb));
      }
#pragma unroll
      for (int fm = 0; fm < 4; ++fm) {
        const int mr = wm * 64 + fm * 16 + (lane & 15);
        bq[fm] = *(const s16x8*)(X + ((mr >> 7) << 14) +
                                 tile_addr(mr & 127, kb));
      }
      __builtin_amdgcn_s_setprio(1);
#pragma unroll
      for (int fc = 0; fc < 8; ++fc)
#pragma unroll
        for (int fm = 0; fm < 4; ++fm)
          acc[fc][fm] = __builtin_amdgcn_mfma_f32_16x16x32_bf16(
              af[fc], bq[fm], acc[fc][fm], 0, 0, 0);
      __builtin_amdgcn_s_setprio(0);
    }
    __syncthreads();  // drains stage loads + all waves' LDS reads
    cur ^= 1;
  }

  u64 best[4] = {~0ull, ~0ull, ~0ull, ~0ull};
#pragma unroll
  for (int fc = 0; fc < 8; ++fc) {
#pragma unroll
    for (int r4 = 0; r4 < 4; ++r4) {
      const int cl = wc * 128 + fc * 16 + (lane >> 4) * 4 + r4;
      const float cs = csq_s[cl];
      const u64 codebits = (u32)(code_base + cl);
#pragma unroll
      for (int fm = 0; fm < 4; ++fm) {
        float d = fmaf(-2.0f, acc[fc][fm][r4], cs);
        u32 u = __float_as_uint(d);
        u = (u & 0x80000000u) ? ~u : (u | 0x80000000u);
        best[fm] = umin64(best[fm], ((u64)u << 32) | codebits);
      }
    }
  }
#pragma unroll
  for (int fm = 0; fm < 4; ++fm) {
    u64 b = best[fm];
#pragma unroll
    for (int off = 16; off < 64; off <<= 1) {
      u32 lo = (u32)b, hi = (u32)(b >> 32);
      lo = (u32)__shfl_xor((int)lo, off, 64);
      hi = (u32)__shfl_xor((int)hi, off, 64);
      b = umin64(b, ((u64)hi << 32) | lo);
    }
    if ((lane >> 4) == 0)
      atomicMin(&packed[row_base + wm * 64 + fm * 16 + (lane & 15)], b);
  }
}

// ---------------------------------------------------------------------------
// pack2: A2 = pool2(x - up1) bf16 + poolb2 (packed bf16, [n][tau][256 u32]).
// Also accumulates scale-1 histogram (idx1[16] tiles p1 disjointly).
__global__ __launch_bounds__(256) void pack2_kernel(
    const float* __restrict__ x, const float* __restrict__ cb,
    const u64* __restrict__ packed, char* __restrict__ a2,
    u32* __restrict__ poolb2, int* __restrict__ hist) {
  __shared__ float rows1[16][516];
  __shared__ int idx1[16];
  const int tid = threadIdx.x;
  const int blk = blockIdx.x;  // 16 n x 128 tiles
  const int n = blk >> 7;
  const int tau0 = (blk & 127) * 8;
  const int tb = tau0 * 2;  // full-res t in [tb, tb+16)
  if (tid < 16) {
    const int id1 = (int)(packed[(size_t)n * TDIM + tb + tid] & 0xffffffffull);
    idx1[tid] = id1;
    atomicAdd(&hist[id1], 1);
  }
  __syncthreads();
  {
    const int rj = tid >> 4, c16 = tid & 15;
    const float* src = cb + (size_t)idx1[rj] * CDIM;
#pragma unroll
    for (int q = 0; q < 8; ++q) {
      const int c = c16 * 4 + q * 64;
      *(f32x4*)&rows1[rj][c] = *(const f32x4*)(src + c);
    }
  }
  __syncthreads();

  const int cg = tid >> 1, half = tid & 1;
  const int c0 = cg * 4;
  const int tl0 = half * 8;  // local t base
  const size_t xbase =
      (size_t)n * (CDIM * TDIM) + (size_t)c0 * TDIM + tb + tl0;

  f32x4 ru[8];
#pragma unroll
  for (int t = 0; t < 8; ++t) ru[t] = *(const f32x4*)&rows1[tl0 + t][c0];

  float p2[4][4];  // [c][q]
#pragma unroll
  for (int j = 0; j < 4; ++j) {
    f32x4 xa = *(const f32x4*)(x + xbase + (size_t)j * TDIM);
    f32x4 xb = *(const f32x4*)(x + xbase + (size_t)j * TDIM + 4);
#pragma unroll
    for (int q = 0; q < 4; ++q) {
      const float e0 = (q < 2) ? xa[2 * q] : xb[2 * q - 4];
      const float e1 = (q < 2) ? xa[2 * q + 1] : xb[2 * q - 3];
      const float r0 = e0 - ru[2 * q][j];
      const float r1 = e1 - ru[2 * q + 1][j];
      p2[j][q] = (r0 + r1) * 0.5f;
    }
  }
  const int kc = c0 >> 6, kbyte = (c0 & 63) * 2;
#pragma unroll
  for (int q = 0; q < 4; ++q) {
    const int tau = tau0 + half * 4 + q;
    i32x2 o = {(int)pack2ch(p2[0][q], p2[1][q]),
               (int)pack2ch(p2[2][q], p2[3][q])};
    // poolb2 (same bits)
    *(i32x2*)(poolb2 + (size_t)n * (1024 * 256) + (size_t)tau * 256 +
              (c0 >> 1)) = o;
    // a2 tile
    const int m = n * 1024 + tau;
    *(i32x2*)(a2 + (((size_t)((m >> 7) * 8 + kc)) << 14) +
              tile_addr(m & 127, kbyte)) = o;
  }
}

// ---------------------------------------------------------------------------
// packN: pool chain at coarse res; pin/pout are packed-bf16 [n][T*][256 u32].
// Also accumulates input-scale histogram (idxs[1..17) tiles disjointly).
template <int TP, bool WPOOL>
__global__ __launch_bounds__(256) void packN_kernel(
    const u32* __restrict__ pin, const float* __restrict__ cb,
    const u64* __restrict__ packed, char* __restrict__ a_next,
    u32* __restrict__ pout, int* __restrict__ hist) {
  constexpr int OFF = (TP == 1024) ? 32768 : 49152;  // scale-2 / scale-4 idx
  constexpr int TILES = TP / 16;
  constexpr int TO = TP / 2;
  __shared__ float rows[18][516];
  __shared__ int idxs[18];
  const int tid = threadIdx.x;
  const int blk = blockIdx.x;  // 16 n x TILES
  const int n = blk / TILES;
  const int o0 = (blk % TILES) * 8;  // output tau base
  const int s0 = o0 * 2;             // input sigma base
  if (tid < 18) {
    const int sig = iclamp(s0 - 1 + tid, 0, TP - 1);
    const int id = (int)(packed[OFF + (size_t)n * TP + sig] & 0xffffffffull);
    idxs[tid] = id;
    if (tid >= 1 && tid < 17) atomicAdd(&hist[id], 1);  // disjoint exact cover
  }
  __syncthreads();
  for (int j = 0; j < 18; ++j) {
    const int c = tid * 2;
    const float* src = cb + (size_t)idxs[j] * CDIM + c;
    rows[j][c] = src[0];
    rows[j][c + 1] = src[1];
  }
  __syncthreads();

  const int cg = tid >> 1, half = tid & 1;
  const int c0 = cg * 4;
  f32x4 inv[8];
#pragma unroll
  for (int l = 0; l < 8; ++l) {
    i32x2 v = *(const i32x2*)(pin + (size_t)n * (TP * 256) +
                              (size_t)(s0 + half * 8 + l) * 256 + (c0 >> 1));
    inv[l][0] = bflo((u32)v[0]);
    inv[l][1] = bfhi((u32)v[0]);
    inv[l][2] = bflo((u32)v[1]);
    inv[l][3] = bfhi((u32)v[1]);
  }

  float pv[4][4];
#pragma unroll
  for (int q = 0; q < 4; ++q) {
    const int e = half * 8 + 2 * q;
    const int sa = e + 1, sb = e + 2;
    f32x4 Rm = *(const f32x4*)&rows[sa - 1][c0];
    f32x4 Rc = *(const f32x4*)&rows[sa][c0];
    f32x4 Rp = *(const f32x4*)&rows[sb][c0];
    f32x4 Rpp = *(const f32x4*)&rows[sb + 1][c0];
    f32x4 ua = 0.125f * (Rm + Rp) + 0.75f * Rc;
    f32x4 ub = 0.125f * (Rc + Rpp) + 0.75f * Rp;
#pragma unroll
    for (int j = 0; j < 4; ++j)
      pv[j][q] = ((inv[2 * q][j] - ua[j]) + (inv[2 * q + 1][j] - ub[j])) * 0.5f;
  }

  const int kc = c0 >> 6, kbyte = (c0 & 63) * 2;
#pragma unroll
  for (int q = 0; q < 4; ++q) {
    const int tau = o0 + half * 4 + q;
    i32x2 o = {(int)pack2ch(pv[0][q], pv[1][q]),
               (int)pack2ch(pv[2][q], pv[3][q])};
    if constexpr (WPOOL) {
      *(i32x2*)(pout + (size_t)n * (TO * 256) + (size_t)tau * 256 +
                (c0 >> 1)) = o;
    }
    const int m = n * TO + tau;
    *(i32x2*)(a_next + (((size_t)((m >> 7) * 8 + kc)) << 14) +
              tile_addr(m & 127, kbyte)) = o;
  }
}

// ---------------------------------------------------------------------------
// final: full-res pass: 4 per-stage losses + f_hat. No LDS staging; each
// thread processes TWO independent t-quads (2x MLP). Grid 2048.
__global__ __launch_bounds__(256) void final_kernel(
    const float* __restrict__ x, float* __restrict__ out,
    const float* __restrict__ cb, const u64* __restrict__ packed,
    float* __restrict__ lossPart) {
  const int tid = threadIdx.x;
  const int blk = blockIdx.x;  // [n:16][t32:64][ch:2]
  const int ch = blk & 1;
  const int t0 = ((blk >> 1) & 63) * 32;
  const int n = blk >> 7;
  const int cg = tid >> 2, qt = tid & 3;
  const int c0 = ch * 256 + cg * 4;
  const int tbA = t0 + qt * 4;
  const int tbB = t0 + 16 + qt * 4;

  const u64* ip1 = packed + (size_t)n * TDIM;
  const u64* ip2 = packed + 32768 + (size_t)n * 1024;
  const u64* ip4 = packed + 49152 + (size_t)n * 512;
  const u64* ip8 = packed + 57344 + (size_t)n * 256;

  // --- gather both tiles' code-row windows (interleaved for MLP) ---
  f32x4 R1A[4], R2A[4], R4A[3], R8A[2];
  f32x4 R1B[4], R2B[4], R4B[3], R8B[2];
#pragma unroll
  for (int k = 0; k < 4; ++k) {
    R1A[k] = *(const f32x4*)(
        cb + (size_t)(u32)(ip1[tbA + k] & 0xffffffffull) * CDIM + c0);
    R1B[k] = *(const f32x4*)(
        cb + (size_t)(u32)(ip1[tbB + k] & 0xffffffffull) * CDIM + c0);
  }
  const int b2A = tbA >> 1, b2B = tbB >> 1;
#pragma unroll
  for (int k = 0; k < 4; ++k) {
    R2A[k] = *(const f32x4*)(
        cb + (size_t)(u32)(ip2[iclamp(b2A - 1 + k, 0, 1023)] & 0xffffffffull) *
                 CDIM + c0);
    R2B[k] = *(const f32x4*)(
        cb + (size_t)(u32)(ip2[iclamp(b2B - 1 + k, 0, 1023)] & 0xffffffffull) *
                 CDIM + c0);
  }
  const int b4A = tbA >> 2, b4B = tbB >> 2;
#pragma unroll
  for (int k = 0; k < 3; ++k) {
    R4A[k] = *(const f32x4*)(
        cb + (size_t)(u32)(ip4[iclamp(b4A - 1 + k, 0, 511)] & 0xffffffffull) *
                 CDIM + c0);
    R4B[k] = *(const f32x4*)(
        cb + (size_t)(u32)(ip4[iclamp(b4B - 1 + k, 0, 511)] & 0xffffffffull) *
                 CDIM + c0);
  }
  const int b8A = (tbA >> 3) - 1 + ((tbA >> 2) & 1);
  const int b8B = (tbB >> 3) - 1 + ((tbB >> 2) & 1);
#pragma unroll
  for (int k = 0; k < 2; ++k) {
    R8A[k] = *(const f32x4*)(
        cb + (size_t)(u32)(ip8[iclamp(b8A + k, 0, 255)] & 0xffffffffull) *
                 CDIM + c0);
    R8B[k] = *(const f32x4*)(
        cb + (size_t)(u32)(ip8[iclamp(b8B + k, 0, 255)] & 0xffffffffull) *
                 CDIM + c0);
  }

  const size_t xbaseA = (size_t)n * (CDIM * TDIM) + (size_t)c0 * TDIM + tbA;
  const size_t xbaseB = xbaseA + 16;
  f32x4 xaA[4], xaB[4], faA[4], faB[4];
#pragma unroll
  for (int j = 0; j < 4; ++j) {
    xaA[j] = *(const f32x4*)(x + xbaseA + (size_t)j * TDIM);
    xaB[j] = *(const f32x4*)(x + xbaseB + (size_t)j * TDIM);
  }

  // per-tt slot/weight tables (tb ≡ 0 mod 4)
  const int s2n[4] = {0, 1, 1, 2};
  const float w2n[4] = {0.75f, 0.25f, 0.75f, 0.25f};
  const int s4n[4] = {0, 0, 1, 1};
  const float w4n[4] = {0.625f, 0.875f, 0.125f, 0.375f};
  const float w8bA = (tbA & 4) ? 0.0625f : 0.5625f;
  const float w8bB = (tbB & 4) ? 0.0625f : 0.5625f;

  float ss1 = 0.f, ss2 = 0.f, ss3 = 0.f, ss4 = 0.f;
#pragma unroll
  for (int tt = 0; tt < 4; ++tt) {
    // tile A
    {
      f32x4 u2 = R2A[s2n[tt]] * (1.f - w2n[tt]) + R2A[s2n[tt] + 1] * w2n[tt];
      f32x4 u4 = R4A[s4n[tt]] * (1.f - w4n[tt]) + R4A[s4n[tt] + 1] * w4n[tt];
      const float w8 = w8bA + tt * 0.125f;
      f32x4 u8 = R8A[0] * (1.f - w8) + R8A[1] * w8;
      f32x4 xv;
#pragma unroll
      for (int j = 0; j < 4; ++j) xv[j] = xaA[j][tt];
      f32x4 r1 = xv - R1A[tt];
      f32x4 r2 = r1 - u2;
      f32x4 r3 = r2 - u4;
      f32x4 r4 = r3 - u8;
#pragma unroll
      for (int j = 0; j < 4; ++j) {
        ss1 += r1[j] * r1[j];
        ss2 += r2[j] * r2[j];
        ss3 += r3[j] * r3[j];
        ss4 += r4[j] * r4[j];
      }
      f32x4 fh = xv - r4;
#pragma unroll
      for (int j = 0; j < 4; ++j) faA[j][tt] = fh[j];
    }
    // tile B
    {
      f32x4 u2 = R2B[s2n[tt]] * (1.f - w2n[tt]) + R2B[s2n[tt] + 1] * w2n[tt];
      f32x4 u4 = R4B[s4n[tt]] * (1.f - w4n[tt]) + R4B[s4n[tt] + 1] * w4n[tt];
      const float w8 = w8bB + tt * 0.125f;
      f32x4 u8 = R8B[0] * (1.f - w8) + R8B[1] * w8;
      f32x4 xv;
#pragma unroll
      for (int j = 0; j < 4; ++j) xv[j] = xaB[j][tt];
      f32x4 r1 = xv - R1B[tt];
      f32x4 r2 = r1 - u2;
      f32x4 r3 = r2 - u4;
      f32x4 r4 = r3 - u8;
#pragma unroll
      for (int j = 0; j < 4; ++j) {
        ss1 += r1[j] * r1[j];
        ss2 += r2[j] * r2[j];
        ss3 += r3[j] * r3[j];
        ss4 += r4[j] * r4[j];
      }
      f32x4 fh = xv - r4;
#pragma unroll
      for (int j = 0; j < 4; ++j) faB[j][tt] = fh[j];
    }
  }
#pragma unroll
  for (int j = 0; j < 4; ++j) {
    *(f32x4*)(out + xbaseA + (size_t)j * TDIM) = faA[j];
    *(f32x4*)(out + xbaseB + (size_t)j * TDIM) = faB[j];
  }

  __shared__ float red2[4][4];
  float sv[4] = {ss1, ss2, ss3, ss4};
  const int w = tid >> 6, lane = tid & 63;
#pragma unroll
  for (int st = 0; st < 4; ++st) {
    float v = sv[st];
#pragma unroll
    for (int off = 32; off; off >>= 1) v += __shfl_down(v, off, 64);
    if (lane == 0) red2[w][st] = v;
  }
  __syncthreads();
  if (tid < 4)
    lossPart[tid * 2048 + blk] =
        red2[0][tid] + red2[1][tid] + red2[2][tid] + red2[3][tid];
}

// ---------------------------------------------------------------------------
// finalize: loss sum + scale-8 histogram (4096 entries, LDS) + perplexity.
__global__ __launch_bounds__(256) void finalize_kernel(
    const float* __restrict__ lossPart, const int* __restrict__ hist,
    const u64* __restrict__ p8, float* __restrict__ outTail) {
  __shared__ float red[4];
  __shared__ int lhist[KCODE];
  const int tid = threadIdx.x;
  for (int k = tid; k < KCODE; k += 256) lhist[k] = 0;
  __syncthreads();
  for (int i = tid; i < 4096; i += 256) {
    const int code = (int)(p8[i] & 0xffffffffull);
    atomicAdd(&lhist[code], 1);
  }
  float s = 0.f;
  for (int i = tid; i < 4 * 2048; i += 256) s += lossPart[i];
#pragma unroll
  for (int off = 32; off; off >>= 1) s += __shfl_down(s, off, 64);
  if ((tid & 63) == 0) red[tid >> 6] = s;
  __syncthreads();
  const float loss =
      (red[0] + red[1] + red[2] + red[3]) * (1.0f / (4.0f * 16777216.0f));
  __syncthreads();
  float e = 0.f;
  for (int k = tid; k < KCODE; k += 256) {
    float p = (float)(hist[k] + lhist[k]) * (1.0f / 61440.0f);
    e += p * logf(p + 1e-7f);
  }
#pragma unroll
  for (int off = 32; off; off >>= 1) e += __shfl_down(e, off, 64);
  if ((tid & 63) == 0) red[tid >> 6] = e;
  __syncthreads();
  if (tid == 0) {
    outTail[0] = loss;
    outTail[1] = expf(-(red[0] + red[1] + red[2] + red[3]));
  }
}

// ---------------------------------------------------------------------------
extern "C" void kernel_launch(void* const* d_in, const int* in_sizes, int n_in,
                              void* d_out, int out_size, void* d_ws,
                              size_t ws_size, hipStream_t stream) {
  const float* x = (const float*)d_in[0];
  const float* cb = (const float*)d_in[1];
  float* out = (float*)d_out;

  char* ws = (char*)d_ws;
  u64* packed = (u64*)ws;                   // 491520 B
  float* csq = (float*)(ws + 491520);       // 4096 B
  int* hist = (int*)(ws + 495616);          // 4096 B
  float* lossPart = (float*)(ws + 499712);  // 32768 B (4 x 2048)
  char* cb_pack = ws + 565248;              // 1 MiB
  char* a2 = ws + (2ull << 20);             // 16 MiB
  char* a4 = ws + (18ull << 20);            // 8 MiB
  char* a8 = ws + (26ull << 20);            // 4 MiB

  u64* p1 = packed;          // 32768 rows (t_s=2048)
  u64* p2 = packed + 32768;  // 16384 rows
  u64* p4 = packed + 49152;  //  8192 rows
  u64* p8 = packed + 57344;  //  4096 rows

  // d_out region reuse: A1 (32MB) until gemm1; then poolb2 [0,16MB) +
  // poolb4 [16,24MB) (packed bf16); finally f_hat overwrites everything.
  char* a1 = (char*)out;
  u32* poolb2 = (u32*)out;            // [n][1024][256 u32] = 16 MB
  u32* poolb4 = (u32*)out + 4194304;  // [n][512][256 u32]  =  8 MB

  prep_kernel<<<1536, 256, 0, stream>>>(cb, cb_pack, csq, x, a1, packed, hist);
  gemm_argmin_packed<<<128 * 4, 512, 0, stream>>>(a1, cb_pack, csq, p1);
  pack2_kernel<<<2048, 256, 0, stream>>>(x, cb, packed, a2, poolb2, hist);
  gemm_argmin_packed<<<64 * 4, 512, 0, stream>>>(a2, cb_pack, csq, p2);
  packN_kernel<1024, true>
      <<<1024, 256, 0, stream>>>(poolb2, cb, packed, a4, poolb4, hist);
  gemm_argmin_packed<<<32 * 4, 512, 0, stream>>>(a4, cb_pack, csq, p4);
  packN_kernel<512, false>
      <<<512, 256, 0, stream>>>(poolb4, cb, packed, a8, nullptr, hist);
  gemm_argmin_packed<<<16 * 4, 512, 0, stream>>>(a8, cb_pack, csq, p8);
  final_kernel<<<2048, 256, 0, stream>>>(x, out, cb, packed, lossPart);
  finalize_kernel<<<1, 256, 0, stream>>>(lossPart, hist, p8, out + FH_ELEMS);
}

// Round 19
// 207.065 us; speedup vs baseline: 1.2789x; 1.0594x over previous
//
#include <hip/hip_runtime.h>

#define CDIM 512
#define TDIM 2048
#define KCODE 1024
#define NTOT 16
#define FH_ELEMS (NTOT * CDIM * TDIM)   // 16777216
#define M_TOTAL 61440                   // 16*(2048+1024+512+256)

typedef unsigned long long u64;
typedef unsigned int u32;
typedef __attribute__((ext_vector_type(8))) short s16x8;
typedef __attribute__((ext_vector_type(4))) float f32x4;
typedef __attribute__((ext_vector_type(4))) int i32x4;
typedef __attribute__((ext_vector_type(2))) int i32x2;

__device__ __forceinline__ u64 umin64(u64 a, u64 b) { return a < b ? a : b; }

// round-to-nearest-even fp32 -> bf16 bits
__device__ __forceinline__ u32 bf16_rne(float f) {
  u32 u = __float_as_uint(f);
  return (u + 0x7fffu + ((u >> 16) & 1u)) >> 16;
}
// pack two consecutive channels into one u32 (low16 = even channel)
__device__ __forceinline__ u32 pack2ch(float v0, float v1) {
  return bf16_rne(v0) | (bf16_rne(v1) << 16);
}
// unpack bf16 pair
__device__ __forceinline__ float bflo(u32 u) { return __uint_as_float(u << 16); }
__device__ __forceinline__ float bfhi(u32 u) {
  return __uint_as_float(u & 0xffff0000u);
}
// byte offset of (m_local row, kbyte) inside a 16KB tile, XOR-swizzled
__device__ __forceinline__ int tile_addr(int ml, int kbyte) {
  return (ml * 128 + kbyte) ^ ((ml & 7) << 4);
}
__device__ __forceinline__ int iclamp(int v, int lo, int hi) {
  return v < lo ? lo : (v > hi ? hi : v);
}

// ---------------------------------------------------------------------------
// prep (merged): blocks [0,256)   = codebook bf16 pack (tiled, XOR-swizzled)
//                blocks [256,512) = csq + packed 0xFF init + hist zeroing
//                blocks [512,1536)= A1 pack of x + poolx = pool2(x) bf16
__global__ __launch_bounds__(256) void prep_kernel(
    const float* __restrict__ cb, char* __restrict__ cb_pack,
    float* __restrict__ csq, const float* __restrict__ x,
    char* __restrict__ a1, u64* __restrict__ packed, int* __restrict__ hist,
    u32* __restrict__ poolx) {
  const int tid = threadIdx.x;
  const int b = blockIdx.x;
  if (b < 256) {
    const int g = b * 256 + tid;  // 65536 threads x 16B = 1MB
    const int tile = g >> 10;
    const int L = (g & 1023) * 16;
    const int nt = tile >> 3, kc = tile & 7;
    const int code_local = L >> 7;
    const int kbyte = (L & 127) ^ ((code_local & 7) << 4);
    const int code = nt * 128 + code_local;
    const int c0 = kc * 64 + (kbyte >> 1);
    f32x4 va = *(const f32x4*)(cb + (size_t)code * CDIM + c0);
    f32x4 vb = *(const f32x4*)(cb + (size_t)code * CDIM + c0 + 4);
    i32x4 o = {(int)pack2ch(va[0], va[1]), (int)pack2ch(va[2], va[3]),
               (int)pack2ch(vb[0], vb[1]), (int)pack2ch(vb[2], vb[3])};
    *(i32x4*)(cb_pack + (size_t)g * 16) = o;
  } else if (b < 512) {
    const int bb = b - 256;
    if (bb < 240) packed[bb * 256 + tid] = ~0ull;  // exact cover of 61440
    if (bb < 4) hist[bb * 256 + tid] = 0;
    const int code = bb * 4 + (tid >> 6);
    const int t = tid & 63;
    const float* row = cb + (size_t)code * CDIM;
    float s = 0.f;
#pragma unroll
    for (int q = 0; q < 2; ++q) {
      float4 v = *(const float4*)(row + (t * 2 + q) * 4);
      s += v.x * v.x + v.y * v.y + v.z * v.z + v.w * v.w;
    }
#pragma unroll
    for (int off = 32; off; off >>= 1) s += __shfl_down(s, off, 64);
    if (t == 0) csq[code] = s;
  } else {
    const int blk = b - 512;  // [n:16][kc:8][tb:8]
    const int lane = tid & 63, cq = tid >> 6;
    const int tb = blk & 7;
    const int kc = (blk >> 3) & 7;
    const int n = blk >> 6;
    const int c0 = kc * 64 + cq * 16;
    const int t0 = tb * 256 + lane * 4;
    const float* xp = x + (size_t)n * (CDIM * TDIM) + (size_t)c0 * TDIM + t0;
    u32 pk[4][8];
    u32 px[2][8];  // [q][jp]: pool2 over t pairs, packed channel pair
#pragma unroll
    for (int jp = 0; jp < 8; ++jp) {
      f32x4 v0 = *(const f32x4*)(xp + (size_t)(2 * jp) * TDIM);
      f32x4 v1 = *(const f32x4*)(xp + (size_t)(2 * jp + 1) * TDIM);
#pragma unroll
      for (int tt = 0; tt < 4; ++tt) pk[tt][jp] = pack2ch(v0[tt], v1[tt]);
#pragma unroll
      for (int q = 0; q < 2; ++q)
        px[q][jp] = pack2ch((v0[2 * q] + v0[2 * q + 1]) * 0.5f,
                            (v1[2 * q] + v1[2 * q + 1]) * 0.5f);
    }
    const int kbyte = cq * 32;
#pragma unroll
    for (int tt = 0; tt < 4; ++tt) {
      const int m = n * TDIM + t0 + tt;
      const size_t tbase = ((size_t)((m >> 7) * 8 + kc)) << 14;
      i32x4 o1 = {(int)pk[tt][0], (int)pk[tt][1], (int)pk[tt][2],
                  (int)pk[tt][3]};
      i32x4 o2 = {(int)pk[tt][4], (int)pk[tt][5], (int)pk[tt][6],
                  (int)pk[tt][7]};
      *(i32x4*)(a1 + tbase + tile_addr(m & 127, kbyte)) = o1;
      *(i32x4*)(a1 + tbase + tile_addr(m & 127, kbyte + 16)) = o2;
    }
    // poolx [n][1024][256 u32]
    const int col = kc * 32 + cq * 8;
#pragma unroll
    for (int q = 0; q < 2; ++q) {
      const int tau = (t0 >> 1) + q;
      u32* dst = poolx + (size_t)n * (1024 * 256) + (size_t)tau * 256 + col;
      i32x4 oa = {(int)px[q][0], (int)px[q][1], (int)px[q][2], (int)px[q][3]};
      i32x4 ob = {(int)px[q][4], (int)px[q][5], (int)px[q][6], (int)px[q][7]};
      *(i32x4*)dst = oa;
      *(i32x4*)(dst + 4) = ob;
    }
  }
}

// ---------------------------------------------------------------------------
// 256x256 MFMA distance GEMM + argmin, 2-phase double-buffered LDS, single
// barrier per K-step (stage-early). 8 waves = 2(code) x 4(m). grid = nx*4,
// XCD-chunked so the 4 code-tiles of one m-tile share an XCD L2.
// LDS buffer layout: [0:32K) = x rows (m), [32K:64K) = codebook rows.
__global__ __launch_bounds__(512, 2) void gemm_argmin_packed(
    const char* __restrict__ a_pack,   // [m_tiles(128r)][8][16KB]
    const char* __restrict__ cb_pack,  // [8][8][16KB]
    const float* __restrict__ csq,
    u64* __restrict__ packed) {
  __shared__ __align__(16) char smem[131072 + 1024];
  float* csq_s = (float*)(smem + 131072);

  const int id = blockIdx.x;
  const int nxq = gridDim.x >> 5;  // nx/8   (gridDim.x = nx*4)
  const int xcd = id & 7;
  const int rr = id >> 3;
  const int bx = xcd * nxq + (rr >> 2);
  const int by = rr & 3;

  const int tid = threadIdx.x;
  const int lane = tid & 63;
  const int w = tid >> 6;   // 0..7
  const int wc = w >> 2;    // code half (0..1)
  const int wm = w & 3;     // m quarter (0..3)
  const int row_base = bx * 256;
  const int code_base = by * 256;
  if (tid < 256) csq_s[tid] = csq[code_base + tid];

  const f32x4 zero = {0.f, 0.f, 0.f, 0.f};
  f32x4 acc[8][4];
#pragma unroll
  for (int fc = 0; fc < 8; ++fc)
#pragma unroll
    for (int fm = 0; fm < 4; ++fm) acc[fc][fm] = zero;

  const size_t aBase = ((size_t)(bx * 2) * 8) << 14;
  const size_t bBase = ((size_t)(by * 2) * 8) << 14;

  auto stage = [&](int buf, int kc) {
    char* dst = smem + buf * 65536;
    const char* gA0 = a_pack + aBase + ((size_t)kc << 14);
    const char* gA1 = a_pack + aBase + ((size_t)(8 + kc) << 14);
    const char* gB0 = cb_pack + bBase + ((size_t)kc << 14);
    const char* gB1 = cb_pack + bBase + ((size_t)(8 + kc) << 14);
    const int o = tid * 16;
#pragma unroll
    for (int p = 0; p < 2; ++p) {
      const int q = o + p * 8192;
      __builtin_amdgcn_global_load_lds(
          (const __attribute__((address_space(1))) u32*)(gA0 + q),
          (__attribute__((address_space(3))) u32*)(dst + q), 16, 0, 0);
      __builtin_amdgcn_global_load_lds(
          (const __attribute__((address_space(1))) u32*)(gA1 + q),
          (__attribute__((address_space(3))) u32*)(dst + 16384 + q), 16, 0, 0);
      __builtin_amdgcn_global_load_lds(
          (const __attribute__((address_space(1))) u32*)(gB0 + q),
          (__attribute__((address_space(3))) u32*)(dst + 32768 + q), 16, 0, 0);
      __builtin_amdgcn_global_load_lds(
          (const __attribute__((address_space(1))) u32*)(gB1 + q),
          (__attribute__((address_space(3))) u32*)(dst + 49152 + q), 16, 0, 0);
    }
  };

  stage(0, 0);
  __syncthreads();

  int cur = 0;
  for (int kc = 0; kc < 8; ++kc) {
    if (kc < 7) stage(cur ^ 1, kc + 1);  // loads in flight across compute
    const char* X = smem + cur * 65536;  // x rows (m dimension)
    const char* C = X + 32768;           // codebook rows
#pragma unroll
    for (int ks = 0; ks < 2; ++ks) {
      const int kb = ks * 64 + (lane >> 4) * 16;
      s16x8 af[8], bq[4];
#pragma unroll
      for (int fc = 0; fc < 8; ++fc) {
        const int cr = wc * 128 + fc * 16 + (lane & 15);
        af[fc] = *(const s16x8*)(C + ((cr >> 7) << 14) +
                                 tile_addr(cr & 127, kb));
      }
#pragma unroll
      for (int fm = 0; fm < 4; ++fm) {
        const int mr = wm * 64 + fm * 16 + (lane & 15);
        bq[fm] = *(const s16x8*)(X + ((mr >> 7) << 14) +
                                 tile_addr(mr & 127, kb));
      }
      __builtin_amdgcn_s_setprio(1);
#pragma unroll
      for (int fc = 0; fc < 8; ++fc)
#pragma unroll
        for (int fm = 0; fm < 4; ++fm)
          acc[fc][fm] = __builtin_amdgcn_mfma_f32_16x16x32_bf16(
              af[fc], bq[fm], acc[fc][fm], 0, 0, 0);
      __builtin_amdgcn_s_setprio(0);
    }
    __syncthreads();  // drains stage loads + all waves' LDS reads
    cur ^= 1;
  }

  u64 best[4] = {~0ull, ~0ull, ~0ull, ~0ull};
#pragma unroll
  for (int fc = 0; fc < 8; ++fc) {
#pragma unroll
    for (int r4 = 0; r4 < 4; ++r4) {
      const int cl = wc * 128 + fc * 16 + (lane >> 4) * 4 + r4;
      const float cs = csq_s[cl];
      const u64 codebits = (u32)(code_base + cl);
#pragma unroll
      for (int fm = 0; fm < 4; ++fm) {
        float d = fmaf(-2.0f, acc[fc][fm][r4], cs);
        u32 u = __float_as_uint(d);
        u = (u & 0x80000000u) ? ~u : (u | 0x80000000u);
        best[fm] = umin64(best[fm], ((u64)u << 32) | codebits);
      }
    }
  }
#pragma unroll
  for (int fm = 0; fm < 4; ++fm) {
    u64 b = best[fm];
#pragma unroll
    for (int off = 16; off < 64; off <<= 1) {
      u32 lo = (u32)b, hi = (u32)(b >> 32);
      lo = (u32)__shfl_xor((int)lo, off, 64);
      hi = (u32)__shfl_xor((int)hi, off, 64);
      b = umin64(b, ((u64)hi << 32) | lo);
    }
    if ((lane >> 4) == 0)
      atomicMin(&packed[row_base + wm * 64 + fm * 16 + (lane & 15)], b);
  }
}

// ---------------------------------------------------------------------------
// pack2: A2 = poolx - pool2(up1) bf16 + poolb2 (packed bf16).
// Reads poolx (bf16) instead of full-res x. Scale-1 histogram here.
__global__ __launch_bounds__(256) void pack2_kernel(
    const u32* __restrict__ poolx, const float* __restrict__ cb,
    const u64* __restrict__ packed, char* __restrict__ a2,
    u32* __restrict__ poolb2, int* __restrict__ hist) {
  __shared__ float rows1[16][516];
  __shared__ int idx1[16];
  const int tid = threadIdx.x;
  const int blk = blockIdx.x;  // 16 n x 128 tiles
  const int n = blk >> 7;
  const int tau0 = (blk & 127) * 8;
  const int tb = tau0 * 2;  // full-res t in [tb, tb+16)
  if (tid < 16) {
    const int id1 = (int)(packed[(size_t)n * TDIM + tb + tid] & 0xffffffffull);
    idx1[tid] = id1;
    atomicAdd(&hist[id1], 1);
  }
  __syncthreads();
  {
    const int rj = tid >> 4, c16 = tid & 15;
    const float* src = cb + (size_t)idx1[rj] * CDIM;
#pragma unroll
    for (int q = 0; q < 8; ++q) {
      const int c = c16 * 4 + q * 64;
      *(f32x4*)&rows1[rj][c] = *(const f32x4*)(src + c);
    }
  }
  __syncthreads();

  const int cg = tid >> 1, half = tid & 1;
  const int c0 = cg * 4;
  const int tl0 = half * 8;  // local full-res t base

  f32x4 ru[8];
#pragma unroll
  for (int t = 0; t < 8; ++t) ru[t] = *(const f32x4*)&rows1[tl0 + t][c0];

  float p2[4][4];  // [c][q]
#pragma unroll
  for (int q = 0; q < 4; ++q) {
    const int tau = tau0 + half * 4 + q;
    i32x2 pv = *(const i32x2*)(poolx + (size_t)n * (1024 * 256) +
                               (size_t)tau * 256 + (c0 >> 1));
    const float pxv[4] = {bflo((u32)pv[0]), bfhi((u32)pv[0]),
                          bflo((u32)pv[1]), bfhi((u32)pv[1])};
#pragma unroll
    for (int j = 0; j < 4; ++j)
      p2[j][q] = pxv[j] - (ru[2 * q][j] + ru[2 * q + 1][j]) * 0.5f;
  }
  const int kc = c0 >> 6, kbyte = (c0 & 63) * 2;
#pragma unroll
  for (int q = 0; q < 4; ++q) {
    const int tau = tau0 + half * 4 + q;
    i32x2 o = {(int)pack2ch(p2[0][q], p2[1][q]),
               (int)pack2ch(p2[2][q], p2[3][q])};
    // poolb2 (same bits)
    *(i32x2*)(poolb2 + (size_t)n * (1024 * 256) + (size_t)tau * 256 +
              (c0 >> 1)) = o;
    // a2 tile
    const int m = n * 1024 + tau;
    *(i32x2*)(a2 + (((size_t)((m >> 7) * 8 + kc)) << 14) +
              tile_addr(m & 127, kbyte)) = o;
  }
}

// ---------------------------------------------------------------------------
// packN: pool chain at coarse res; pin/pout are packed-bf16 [n][T*][256 u32].
// Also accumulates input-scale histogram (idxs[1..17) tiles disjointly).
template <int TP, bool WPOOL>
__global__ __launch_bounds__(256) void packN_kernel(
    const u32* __restrict__ pin, const float* __restrict__ cb,
    const u64* __restrict__ packed, char* __restrict__ a_next,
    u32* __restrict__ pout, int* __restrict__ hist) {
  constexpr int OFF = (TP == 1024) ? 32768 : 49152;  // scale-2 / scale-4 idx
  constexpr int TILES = TP / 16;
  constexpr int TO = TP / 2;
  __shared__ float rows[18][516];
  __shared__ int idxs[18];
  const int tid = threadIdx.x;
  const int blk = blockIdx.x;  // 16 n x TILES
  const int n = blk / TILES;
  const int o0 = (blk % TILES) * 8;  // output tau base
  const int s0 = o0 * 2;             // input sigma base
  if (tid < 18) {
    const int sig = iclamp(s0 - 1 + tid, 0, TP - 1);
    const int id = (int)(packed[OFF + (size_t)n * TP + sig] & 0xffffffffull);
    idxs[tid] = id;
    if (tid >= 1 && tid < 17) atomicAdd(&hist[id], 1);  // disjoint exact cover
  }
  __syncthreads();
  for (int j = 0; j < 18; ++j) {
    const int c = tid * 2;
    const float* src = cb + (size_t)idxs[j] * CDIM + c;
    rows[j][c] = src[0];
    rows[j][c + 1] = src[1];
  }
  __syncthreads();

  const int cg = tid >> 1, half = tid & 1;
  const int c0 = cg * 4;
  f32x4 inv[8];
#pragma unroll
  for (int l = 0; l < 8; ++l) {
    i32x2 v = *(const i32x2*)(pin + (size_t)n * (TP * 256) +
                              (size_t)(s0 + half * 8 + l) * 256 + (c0 >> 1));
    inv[l][0] = bflo((u32)v[0]);
    inv[l][1] = bfhi((u32)v[0]);
    inv[l][2] = bflo((u32)v[1]);
    inv[l][3] = bfhi((u32)v[1]);
  }

  float pv[4][4];
#pragma unroll
  for (int q = 0; q < 4; ++q) {
    const int e = half * 8 + 2 * q;
    const int sa = e + 1, sb = e + 2;
    f32x4 Rm = *(const f32x4*)&rows[sa - 1][c0];
    f32x4 Rc = *(const f32x4*)&rows[sa][c0];
    f32x4 Rp = *(const f32x4*)&rows[sb][c0];
    f32x4 Rpp = *(const f32x4*)&rows[sb + 1][c0];
    f32x4 ua = 0.125f * (Rm + Rp) + 0.75f * Rc;
    f32x4 ub = 0.125f * (Rc + Rpp) + 0.75f * Rp;
#pragma unroll
    for (int j = 0; j < 4; ++j)
      pv[j][q] = ((inv[2 * q][j] - ua[j]) + (inv[2 * q + 1][j] - ub[j])) * 0.5f;
  }

  const int kc = c0 >> 6, kbyte = (c0 & 63) * 2;
#pragma unroll
  for (int q = 0; q < 4; ++q) {
    const int tau = o0 + half * 4 + q;
    i32x2 o = {(int)pack2ch(pv[0][q], pv[1][q]),
               (int)pack2ch(pv[2][q], pv[3][q])};
    if constexpr (WPOOL) {
      *(i32x2*)(pout + (size_t)n * (TO * 256) + (size_t)tau * 256 +
                (c0 >> 1)) = o;
    }
    const int m = n * TO + tau;
    *(i32x2*)(a_next + (((size_t)((m >> 7) * 8 + kc)) << 14) +
              tile_addr(m & 127, kbyte)) = o;
  }
}

// ---------------------------------------------------------------------------
// final: full-res pass: 4 per-stage losses + f_hat. No LDS staging; each
// thread processes TWO independent t-quads (2x MLP). Grid 2048.
__global__ __launch_bounds__(256) void final_kernel(
    const float* __restrict__ x, float* __restrict__ out,
    const float* __restrict__ cb, const u64* __restrict__ packed,
    float* __restrict__ lossPart) {
  const int tid = threadIdx.x;
  const int blk = blockIdx.x;  // [n:16][t32:64][ch:2]
  const int ch = blk & 1;
  const int t0 = ((blk >> 1) & 63) * 32;
  const int n = blk >> 7;
  const int cg = tid >> 2, qt = tid & 3;
  const int c0 = ch * 256 + cg * 4;
  const int tbA = t0 + qt * 4;
  const int tbB = t0 + 16 + qt * 4;

  const u64* ip1 = packed + (size_t)n * TDIM;
  const u64* ip2 = packed + 32768 + (size_t)n * 1024;
  const u64* ip4 = packed + 49152 + (size_t)n * 512;
  const u64* ip8 = packed + 57344 + (size_t)n * 256;

  // --- gather both tiles' code-row windows (interleaved for MLP) ---
  f32x4 R1A[4], R2A[4], R4A[3], R8A[2];
  f32x4 R1B[4], R2B[4], R4B[3], R8B[2];
#pragma unroll
  for (int k = 0; k < 4; ++k) {
    R1A[k] = *(const f32x4*)(
        cb + (size_t)(u32)(ip1[tbA + k] & 0xffffffffull) * CDIM + c0);
    R1B[k] = *(const f32x4*)(
        cb + (size_t)(u32)(ip1[tbB + k] & 0xffffffffull) * CDIM + c0);
  }
  const int b2A = tbA >> 1, b2B = tbB >> 1;
#pragma unroll
  for (int k = 0; k < 4; ++k) {
    R2A[k] = *(const f32x4*)(
        cb + (size_t)(u32)(ip2[iclamp(b2A - 1 + k, 0, 1023)] & 0xffffffffull) *
                 CDIM + c0);
    R2B[k] = *(const f32x4*)(
        cb + (size_t)(u32)(ip2[iclamp(b2B - 1 + k, 0, 1023)] & 0xffffffffull) *
                 CDIM + c0);
  }
  const int b4A = tbA >> 2, b4B = tbB >> 2;
#pragma unroll
  for (int k = 0; k < 3; ++k) {
    R4A[k] = *(const f32x4*)(
        cb + (size_t)(u32)(ip4[iclamp(b4A - 1 + k, 0, 511)] & 0xffffffffull) *
                 CDIM + c0);
    R4B[k] = *(const f32x4*)(
        cb + (size_t)(u32)(ip4[iclamp(b4B - 1 + k, 0, 511)] & 0xffffffffull) *
                 CDIM + c0);
  }
  const int b8A = (tbA >> 3) - 1 + ((tbA >> 2) & 1);
  const int b8B = (tbB >> 3) - 1 + ((tbB >> 2) & 1);
#pragma unroll
  for (int k = 0; k < 2; ++k) {
    R8A[k] = *(const f32x4*)(
        cb + (size_t)(u32)(ip8[iclamp(b8A + k, 0, 255)] & 0xffffffffull) *
                 CDIM + c0);
    R8B[k] = *(const f32x4*)(
        cb + (size_t)(u32)(ip8[iclamp(b8B + k, 0, 255)] & 0xffffffffull) *
                 CDIM + c0);
  }

  const size_t xbaseA = (size_t)n * (CDIM * TDIM) + (size_t)c0 * TDIM + tbA;
  const size_t xbaseB = xbaseA + 16;
  f32x4 xaA[4], xaB[4], faA[4], faB[4];
#pragma unroll
  for (int j = 0; j < 4; ++j) {
    xaA[j] = *(const f32x4*)(x + xbaseA + (size_t)j * TDIM);
    xaB[j] = *(const f32x4*)(x + xbaseB + (size_t)j * TDIM);
  }

  // per-tt slot/weight tables (tb ≡ 0 mod 4)
  const int s2n[4] = {0, 1, 1, 2};
  const float w2n[4] = {0.75f, 0.25f, 0.75f, 0.25f};
  const int s4n[4] = {0, 0, 1, 1};
  const float w4n[4] = {0.625f, 0.875f, 0.125f, 0.375f};
  const float w8bA = (tbA & 4) ? 0.0625f : 0.5625f;
  const float w8bB = (tbB & 4) ? 0.0625f : 0.5625f;

  float ss1 = 0.f, ss2 = 0.f, ss3 = 0.f, ss4 = 0.f;
#pragma unroll
  for (int tt = 0; tt < 4; ++tt) {
    // tile A
    {
      f32x4 u2 = R2A[s2n[tt]] * (1.f - w2n[tt]) + R2A[s2n[tt] + 1] * w2n[tt];
      f32x4 u4 = R4A[s4n[tt]] * (1.f - w4n[tt]) + R4A[s4n[tt] + 1] * w4n[tt];
      const float w8 = w8bA + tt * 0.125f;
      f32x4 u8 = R8A[0] * (1.f - w8) + R8A[1] * w8;
      f32x4 xv;
#pragma unroll
      for (int j = 0; j < 4; ++j) xv[j] = xaA[j][tt];
      f32x4 r1 = xv - R1A[tt];
      f32x4 r2 = r1 - u2;
      f32x4 r3 = r2 - u4;
      f32x4 r4 = r3 - u8;
#pragma unroll
      for (int j = 0; j < 4; ++j) {
        ss1 += r1[j] * r1[j];
        ss2 += r2[j] * r2[j];
        ss3 += r3[j] * r3[j];
        ss4 += r4[j] * r4[j];
      }
      f32x4 fh = xv - r4;
#pragma unroll
      for (int j = 0; j < 4; ++j) faA[j][tt] = fh[j];
    }
    // tile B
    {
      f32x4 u2 = R2B[s2n[tt]] * (1.f - w2n[tt]) + R2B[s2n[tt] + 1] * w2n[tt];
      f32x4 u4 = R4B[s4n[tt]] * (1.f - w4n[tt]) + R4B[s4n[tt] + 1] * w4n[tt];
      const float w8 = w8bB + tt * 0.125f;
      f32x4 u8 = R8B[0] * (1.f - w8) + R8B[1] * w8;
      f32x4 xv;
#pragma unroll
      for (int j = 0; j < 4; ++j) xv[j] = xaB[j][tt];
      f32x4 r1 = xv - R1B[tt];
      f32x4 r2 = r1 - u2;
      f32x4 r3 = r2 - u4;
      f32x4 r4 = r3 - u8;
#pragma unroll
      for (int j = 0; j < 4; ++j) {
        ss1 += r1[j] * r1[j];
        ss2 += r2[j] * r2[j];
        ss3 += r3[j] * r3[j];
        ss4 += r4[j] * r4[j];
      }
      f32x4 fh = xv - r4;
#pragma unroll
      for (int j = 0; j < 4; ++j) faB[j][tt] = fh[j];
    }
  }
#pragma unroll
  for (int j = 0; j < 4; ++j) {
    *(f32x4*)(out + xbaseA + (size_t)j * TDIM) = faA[j];
    *(f32x4*)(out + xbaseB + (size_t)j * TDIM) = faB[j];
  }

  __shared__ float red2[4][4];
  float sv[4] = {ss1, ss2, ss3, ss4};
  const int w = tid >> 6, lane = tid & 63;
#pragma unroll
  for (int st = 0; st < 4; ++st) {
    float v = sv[st];
#pragma unroll
    for (int off = 32; off; off >>= 1) v += __shfl_down(v, off, 64);
    if (lane == 0) red2[w][st] = v;
  }
  __syncthreads();
  if (tid < 4)
    lossPart[tid * 2048 + blk] =
        red2[0][tid] + red2[1][tid] + red2[2][tid] + red2[3][tid];
}

// ---------------------------------------------------------------------------
// finalize: loss sum + scale-8 histogram (4096 entries, LDS) + perplexity.
__global__ __launch_bounds__(256) void finalize_kernel(
    const float* __restrict__ lossPart, const int* __restrict__ hist,
    const u64* __restrict__ p8, float* __restrict__ outTail) {
  __shared__ float red[4];
  __shared__ int lhist[KCODE];
  const int tid = threadIdx.x;
  for (int k = tid; k < KCODE; k += 256) lhist[k] = 0;
  __syncthreads();
  for (int i = tid; i < 4096; i += 256) {
    const int code = (int)(p8[i] & 0xffffffffull);
    atomicAdd(&lhist[code], 1);
  }
  float s = 0.f;
  for (int i = tid; i < 4 * 2048; i += 256) s += lossPart[i];
#pragma unroll
  for (int off = 32; off; off >>= 1) s += __shfl_down(s, off, 64);
  if ((tid & 63) == 0) red[tid >> 6] = s;
  __syncthreads();
  const float loss =
      (red[0] + red[1] + red[2] + red[3]) * (1.0f / (4.0f * 16777216.0f));
  __syncthreads();
  float e = 0.f;
  for (int k = tid; k < KCODE; k += 256) {
    float p = (float)(hist[k] + lhist[k]) * (1.0f / 61440.0f);
    e += p * logf(p + 1e-7f);
  }
#pragma unroll
  for (int off = 32; off; off >>= 1) e += __shfl_down(e, off, 64);
  if ((tid & 63) == 0) red[tid >> 6] = e;
  __syncthreads();
  if (tid == 0) {
    outTail[0] = loss;
    outTail[1] = expf(-(red[0] + red[1] + red[2] + red[3]));
  }
}

// ---------------------------------------------------------------------------
extern "C" void kernel_launch(void* const* d_in, const int* in_sizes, int n_in,
                              void* d_out, int out_size, void* d_ws,
                              size_t ws_size, hipStream_t stream) {
  const float* x = (const float*)d_in[0];
  const float* cb = (const float*)d_in[1];
  float* out = (float*)d_out;

  char* ws = (char*)d_ws;
  u64* packed = (u64*)ws;                   // 491520 B
  float* csq = (float*)(ws + 491520);       // 4096 B
  int* hist = (int*)(ws + 495616);          // 4096 B
  float* lossPart = (float*)(ws + 499712);  // 32768 B (4 x 2048)
  char* cb_pack = ws + 565248;              // 1 MiB
  char* a2 = ws + (2ull << 20);             // 16 MiB
  char* a4 = ws + (18ull << 20);            // 8 MiB
  char* a8 = ws + (26ull << 20);            // 4 MiB

  u64* p1 = packed;          // 32768 rows (t_s=2048)
  u64* p2 = packed + 32768;  // 16384 rows
  u64* p4 = packed + 49152;  //  8192 rows
  u64* p8 = packed + 57344;  //  4096 rows

  // d_out region reuse: A1 [0,32MB) + poolx [32,48MB) until pack2; then
  // poolb2 [0,16MB) + poolb4 [16,24MB); finally f_hat overwrites all.
  char* a1 = (char*)out;
  u32* poolx = (u32*)out + 8388608;   // [n][1024][256 u32] = 16 MB @ 32MB
  u32* poolb2 = (u32*)out;            // [n][1024][256 u32] = 16 MB
  u32* poolb4 = (u32*)out + 4194304;  // [n][512][256 u32]  =  8 MB

  prep_kernel<<<1536, 256, 0, stream>>>(cb, cb_pack, csq, x, a1, packed, hist,
                                        poolx);
  gemm_argmin_packed<<<128 * 4, 512, 0, stream>>>(a1, cb_pack, csq, p1);
  pack2_kernel<<<2048, 256, 0, stream>>>(poolx, cb, packed, a2, poolb2, hist);
  gemm_argmin_packed<<<64 * 4, 512, 0, stream>>>(a2, cb_pack, csq, p2);
  packN_kernel<1024, true>
      <<<1024, 256, 0, stream>>>(poolb2, cb, packed, a4, poolb4, hist);
  gemm_argmin_packed<<<32 * 4, 512, 0, stream>>>(a4, cb_pack, csq, p4);
  packN_kernel<512, false>
      <<<512, 256, 0, stream>>>(poolb4, cb, packed, a8, nullptr, hist);
  gemm_argmin_packed<<<16 * 4, 512, 0, stream>>>(a8, cb_pack, csq, p8);
  final_kernel<<<2048, 256, 0, stream>>>(x, out, cb, packed, lossPart);
  finalize_kernel<<<1, 256, 0, stream>>>(lossPart, hist, p8, out + FH_ELEMS);
}

// Round 20
// 201.549 us; speedup vs baseline: 1.3139x; 1.0274x over previous
//
#include <hip/hip_runtime.h>

#define CDIM 512
#define TDIM 2048
#define KCODE 1024
#define NTOT 16
#define FH_ELEMS (NTOT * CDIM * TDIM)   // 16777216
#define M_TOTAL 61440                   // 16*(2048+1024+512+256)

typedef unsigned long long u64;
typedef unsigned int u32;
typedef __attribute__((ext_vector_type(8))) short s16x8;
typedef __attribute__((ext_vector_type(4))) float f32x4;
typedef __attribute__((ext_vector_type(4))) int i32x4;
typedef __attribute__((ext_vector_type(2))) int i32x2;

__device__ __forceinline__ u64 umin64(u64 a, u64 b) { return a < b ? a : b; }

// round-to-nearest-even fp32 -> bf16 bits
__device__ __forceinline__ u32 bf16_rne(float f) {
  u32 u = __float_as_uint(f);
  return (u + 0x7fffu + ((u >> 16) & 1u)) >> 16;
}
// pack two consecutive channels into one u32 (low16 = even channel)
__device__ __forceinline__ u32 pack2ch(float v0, float v1) {
  return bf16_rne(v0) | (bf16_rne(v1) << 16);
}
// unpack bf16 pair
__device__ __forceinline__ float bflo(u32 u) { return __uint_as_float(u << 16); }
__device__ __forceinline__ float bfhi(u32 u) {
  return __uint_as_float(u & 0xffff0000u);
}
// byte offset of (m_local row, kbyte) inside a 16KB tile, XOR-swizzled
__device__ __forceinline__ int tile_addr(int ml, int kbyte) {
  return (ml * 128 + kbyte) ^ ((ml & 7) << 4);
}
__device__ __forceinline__ int iclamp(int v, int lo, int hi) {
  return v < lo ? lo : (v > hi ? hi : v);
}

// ---------------------------------------------------------------------------
// prep (merged): blocks [0,1024)     = A1 pack of x (LDS-transposed writes)
//                                      + poolx = pool2(x) bf16
//                blocks [1024,1280)  = codebook bf16 pack (tiled, swizzled)
//                blocks [1280,1536)  = csq + packed 0xFF init + hist zeroing
__global__ __launch_bounds__(256) void prep_kernel(
    const float* __restrict__ cb, char* __restrict__ cb_pack,
    float* __restrict__ csq, const float* __restrict__ x,
    char* __restrict__ a1, u64* __restrict__ packed, int* __restrict__ hist,
    u32* __restrict__ poolx) {
  __shared__ u32 st[256 * 36];  // [t_local][36] (pad 36: b128-aligned cols)
  const int tid = threadIdx.x;
  const int b = blockIdx.x;
  if (b < 1024) {
    const int blk = b;  // [n:16][kc:8][tb:8]
    const int lane = tid & 63, cq = tid >> 6;
    const int tb = blk & 7;
    const int kc = (blk >> 3) & 7;
    const int n = blk >> 6;
    const int c0 = kc * 64 + cq * 16;
    const int lt0 = lane * 4;           // t_local base
    const int t0 = tb * 256 + lt0;
    const float* xp = x + (size_t)n * (CDIM * TDIM) + (size_t)c0 * TDIM + t0;
    u32 pk[4][8];
    u32 px[2][8];  // [q][jp]: pool2 over t pairs, packed channel pair
#pragma unroll
    for (int jp = 0; jp < 8; ++jp) {
      f32x4 v0 = *(const f32x4*)(xp + (size_t)(2 * jp) * TDIM);
      f32x4 v1 = *(const f32x4*)(xp + (size_t)(2 * jp + 1) * TDIM);
#pragma unroll
      for (int tt = 0; tt < 4; ++tt) pk[tt][jp] = pack2ch(v0[tt], v1[tt]);
#pragma unroll
      for (int q = 0; q < 2; ++q)
        px[q][jp] = pack2ch((v0[2 * q] + v0[2 * q + 1]) * 0.5f,
                            (v1[2 * q] + v1[2 * q + 1]) * 0.5f);
    }
    // phase A: stage packed pairs in LDS [t_local][col], col = kbyte/4
#pragma unroll
    for (int tt = 0; tt < 4; ++tt) {
      u32* dst = &st[(lt0 + tt) * 36 + cq * 8];
      i32x4 oa = {(int)pk[tt][0], (int)pk[tt][1], (int)pk[tt][2],
                  (int)pk[tt][3]};
      i32x4 ob = {(int)pk[tt][4], (int)pk[tt][5], (int)pk[tt][6],
                  (int)pk[tt][7]};
      *(i32x4*)dst = oa;
      *(i32x4*)(dst + 4) = ob;
    }
    // poolx [n][1024][256 u32] (unchanged layout)
    const int col = kc * 32 + cq * 8;
#pragma unroll
    for (int q = 0; q < 2; ++q) {
      const int tau = (t0 >> 1) + q;
      u32* dst = poolx + (size_t)n * (1024 * 256) + (size_t)tau * 256 + col;
      i32x4 oa = {(int)px[q][0], (int)px[q][1], (int)px[q][2], (int)px[q][3]};
      i32x4 ob = {(int)px[q][4], (int)px[q][5], (int)px[q][6], (int)px[q][7]};
      *(i32x4*)dst = oa;
      *(i32x4*)(dst + 4) = ob;
    }
    __syncthreads();
    // phase B: linear 16B stores; inverse-swizzle on the LDS read side
#pragma unroll
    for (int tile = 0; tile < 2; ++tile) {
      const int mt = n * 16 + tb * 2 + tile;
      char* tbase = a1 + (((size_t)(mt * 8 + kc)) << 14);
#pragma unroll
      for (int p = 0; p < 4; ++p) {
        const int L = tid * 16 + p * 4096;
        const int ml = L >> 7;
        const int kbyte = (L & 127) ^ ((ml & 7) << 4);
        const u32* src = &st[(tile * 128 + ml) * 36 + (kbyte >> 2)];
        i32x4 o = {(int)src[0], (int)src[1], (int)src[2], (int)src[3]};
        *(i32x4*)(tbase + L) = o;
      }
    }
  } else if (b < 1280) {
    const int g = (b - 1024) * 256 + tid;  // 65536 threads x 16B = 1MB
    const int tile = g >> 10;
    const int L = (g & 1023) * 16;
    const int nt = tile >> 3, kc = tile & 7;
    const int code_local = L >> 7;
    const int kbyte = (L & 127) ^ ((code_local & 7) << 4);
    const int code = nt * 128 + code_local;
    const int c0 = kc * 64 + (kbyte >> 1);
    f32x4 va = *(const f32x4*)(cb + (size_t)code * CDIM + c0);
    f32x4 vb = *(const f32x4*)(cb + (size_t)code * CDIM + c0 + 4);
    i32x4 o = {(int)pack2ch(va[0], va[1]), (int)pack2ch(va[2], va[3]),
               (int)pack2ch(vb[0], vb[1]), (int)pack2ch(vb[2], vb[3])};
    *(i32x4*)(cb_pack + (size_t)g * 16) = o;
  } else {
    const int bb = b - 1280;
    if (bb < 240) packed[bb * 256 + tid] = ~0ull;  // exact cover of 61440
    if (bb < 4) hist[bb * 256 + tid] = 0;
    const int code = bb * 4 + (tid >> 6);
    const int t = tid & 63;
    const float* row = cb + (size_t)code * CDIM;
    float s = 0.f;
#pragma unroll
    for (int q = 0; q < 2; ++q) {
      float4 v = *(const float4*)(row + (t * 2 + q) * 4);
      s += v.x * v.x + v.y * v.y + v.z * v.z + v.w * v.w;
    }
#pragma unroll
    for (int off = 32; off; off >>= 1) s += __shfl_down(s, off, 64);
    if (t == 0) csq[code] = s;
  }
}

// ---------------------------------------------------------------------------
// 256x256 MFMA distance GEMM + argmin, 2-phase double-buffered LDS, single
// barrier per K-step (stage-early). 8 waves = 2(code) x 4(m). grid = nx*4,
// XCD-chunked so the 4 code-tiles of one m-tile share an XCD L2.
// LDS buffer layout: [0:32K) = x rows (m), [32K:64K) = codebook rows.
__global__ __launch_bounds__(512, 2) void gemm_argmin_packed(
    const char* __restrict__ a_pack,   // [m_tiles(128r)][8][16KB]
    const char* __restrict__ cb_pack,  // [8][8][16KB]
    const float* __restrict__ csq,
    u64* __restrict__ packed) {
  __shared__ __align__(16) char smem[131072 + 1024];
  float* csq_s = (float*)(smem + 131072);

  const int id = blockIdx.x;
  const int nxq = gridDim.x >> 5;  // nx/8   (gridDim.x = nx*4)
  const int xcd = id & 7;
  const int rr = id >> 3;
  const int bx = xcd * nxq + (rr >> 2);
  const int by = rr & 3;

  const int tid = threadIdx.x;
  const int lane = tid & 63;
  const int w = tid >> 6;   // 0..7
  const int wc = w >> 2;    // code half (0..1)
  const int wm = w & 3;     // m quarter (0..3)
  const int row_base = bx * 256;
  const int code_base = by * 256;
  if (tid < 256) csq_s[tid] = csq[code_base + tid];

  const f32x4 zero = {0.f, 0.f, 0.f, 0.f};
  f32x4 acc[8][4];
#pragma unroll
  for (int fc = 0; fc < 8; ++fc)
#pragma unroll
    for (int fm = 0; fm < 4; ++fm) acc[fc][fm] = zero;

  const size_t aBase = ((size_t)(bx * 2) * 8) << 14;
  const size_t bBase = ((size_t)(by * 2) * 8) << 14;

  auto stage = [&](int buf, int kc) {
    char* dst = smem + buf * 65536;
    const char* gA0 = a_pack + aBase + ((size_t)kc << 14);
    const char* gA1 = a_pack + aBase + ((size_t)(8 + kc) << 14);
    const char* gB0 = cb_pack + bBase + ((size_t)kc << 14);
    const char* gB1 = cb_pack + bBase + ((size_t)(8 + kc) << 14);
    const int o = tid * 16;
#pragma unroll
    for (int p = 0; p < 2; ++p) {
      const int q = o + p * 8192;
      __builtin_amdgcn_global_load_lds(
          (const __attribute__((address_space(1))) u32*)(gA0 + q),
          (__attribute__((address_space(3))) u32*)(dst + q), 16, 0, 0);
      __builtin_amdgcn_global_load_lds(
          (const __attribute__((address_space(1))) u32*)(gA1 + q),
          (__attribute__((address_space(3))) u32*)(dst + 16384 + q), 16, 0, 0);
      __builtin_amdgcn_global_load_lds(
          (const __attribute__((address_space(1))) u32*)(gB0 + q),
          (__attribute__((address_space(3))) u32*)(dst + 32768 + q), 16, 0, 0);
      __builtin_amdgcn_global_load_lds(
          (const __attribute__((address_space(1))) u32*)(gB1 + q),
          (__attribute__((address_space(3))) u32*)(dst + 49152 + q), 16, 0, 0);
    }
  };

  stage(0, 0);
  __syncthreads();

  int cur = 0;
  for (int kc = 0; kc < 8; ++kc) {
    if (kc < 7) stage(cur ^ 1, kc + 1);  // loads in flight across compute
    const char* X = smem + cur * 65536;  // x rows (m dimension)
    const char* C = X + 32768;           // codebook rows
#pragma unroll
    for (int ks = 0; ks < 2; ++ks) {
      const int kb = ks * 64 + (lane >> 4) * 16;
      s16x8 af[8], bq[4];
#pragma unroll
      for (int fc = 0; fc < 8; ++fc) {
        const int cr = wc * 128 + fc * 16 + (lane & 15);
        af[fc] = *(const s16x8*)(C + ((cr >> 7) << 14) +
                                 tile_addr(cr & 127, kb));
      }
#pragma unroll
      for (int fm = 0; fm < 4; ++fm) {
        const int mr = wm * 64 + fm * 16 + (lane & 15);
        bq[fm] = *(const s16x8*)(X + ((mr >> 7) << 14) +
                                 tile_addr(mr & 127, kb));
      }
      __builtin_amdgcn_s_setprio(1);
#pragma unroll
      for (int fc = 0; fc < 8; ++fc)
#pragma unroll
        for (int fm = 0; fm < 4; ++fm)
          acc[fc][fm] = __builtin_amdgcn_mfma_f32_16x16x32_bf16(
              af[fc], bq[fm], acc[fc][fm], 0, 0, 0);
      __builtin_amdgcn_s_setprio(0);
    }
    __syncthreads();  // drains stage loads + all waves' LDS reads
    cur ^= 1;
  }

  u64 best[4] = {~0ull, ~0ull, ~0ull, ~0ull};
#pragma unroll
  for (int fc = 0; fc < 8; ++fc) {
#pragma unroll
    for (int r4 = 0; r4 < 4; ++r4) {
      const int cl = wc * 128 + fc * 16 + (lane >> 4) * 4 + r4;
      const float cs = csq_s[cl];
      const u64 codebits = (u32)(code_base + cl);
#pragma unroll
      for (int fm = 0; fm < 4; ++fm) {
        float d = fmaf(-2.0f, acc[fc][fm][r4], cs);
        u32 u = __float_as_uint(d);
        u = (u & 0x80000000u) ? ~u : (u | 0x80000000u);
        best[fm] = umin64(best[fm], ((u64)u << 32) | codebits);
      }
    }
  }
#pragma unroll
  for (int fm = 0; fm < 4; ++fm) {
    u64 b = best[fm];
#pragma unroll
    for (int off = 16; off < 64; off <<= 1) {
      u32 lo = (u32)b, hi = (u32)(b >> 32);
      lo = (u32)__shfl_xor((int)lo, off, 64);
      hi = (u32)__shfl_xor((int)hi, off, 64);
      b = umin64(b, ((u64)hi << 32) | lo);
    }
    if ((lane >> 4) == 0)
      atomicMin(&packed[row_base + wm * 64 + fm * 16 + (lane & 15)], b);
  }
}

// ---------------------------------------------------------------------------
// pack2: A2 = poolx - pool2(up1) bf16 + poolb2 (packed bf16).
// Reads poolx (bf16) instead of full-res x. Scale-1 histogram here.
__global__ __launch_bounds__(256) void pack2_kernel(
    const u32* __restrict__ poolx, const float* __restrict__ cb,
    const u64* __restrict__ packed, char* __restrict__ a2,
    u32* __restrict__ poolb2, int* __restrict__ hist) {
  __shared__ float rows1[16][516];
  __shared__ int idx1[16];
  const int tid = threadIdx.x;
  const int blk = blockIdx.x;  // 16 n x 128 tiles
  const int n = blk >> 7;
  const int tau0 = (blk & 127) * 8;
  const int tb = tau0 * 2;  // full-res t in [tb, tb+16)
  if (tid < 16) {
    const int id1 = (int)(packed[(size_t)n * TDIM + tb + tid] & 0xffffffffull);
    idx1[tid] = id1;
    atomicAdd(&hist[id1], 1);
  }
  __syncthreads();
  {
    const int rj = tid >> 4, c16 = tid & 15;
    const float* src = cb + (size_t)idx1[rj] * CDIM;
#pragma unroll
    for (int q = 0; q < 8; ++q) {
      const int c = c16 * 4 + q * 64;
      *(f32x4*)&rows1[rj][c] = *(const f32x4*)(src + c);
    }
  }
  __syncthreads();

  const int cg = tid >> 1, half = tid & 1;
  const int c0 = cg * 4;
  const int tl0 = half * 8;  // local full-res t base

  f32x4 ru[8];
#pragma unroll
  for (int t = 0; t < 8; ++t) ru[t] = *(const f32x4*)&rows1[tl0 + t][c0];

  float p2[4][4];  // [c][q]
#pragma unroll
  for (int q = 0; q < 4; ++q) {
    const int tau = tau0 + half * 4 + q;
    i32x2 pv = *(const i32x2*)(poolx + (size_t)n * (1024 * 256) +
                               (size_t)tau * 256 + (c0 >> 1));
    const float pxv[4] = {bflo((u32)pv[0]), bfhi((u32)pv[0]),
                          bflo((u32)pv[1]), bfhi((u32)pv[1])};
#pragma unroll
    for (int j = 0; j < 4; ++j)
      p2[j][q] = pxv[j] - (ru[2 * q][j] + ru[2 * q + 1][j]) * 0.5f;
  }
  const int kc = c0 >> 6, kbyte = (c0 & 63) * 2;
#pragma unroll
  for (int q = 0; q < 4; ++q) {
    const int tau = tau0 + half * 4 + q;
    i32x2 o = {(int)pack2ch(p2[0][q], p2[1][q]),
               (int)pack2ch(p2[2][q], p2[3][q])};
    // poolb2 (same bits)
    *(i32x2*)(poolb2 + (size_t)n * (1024 * 256) + (size_t)tau * 256 +
              (c0 >> 1)) = o;
    // a2 tile
    const int m = n * 1024 + tau;
    *(i32x2*)(a2 + (((size_t)((m >> 7) * 8 + kc)) << 14) +
              tile_addr(m & 127, kbyte)) = o;
  }
}

// ---------------------------------------------------------------------------
// packN: pool chain at coarse res; pin/pout are packed-bf16 [n][T*][256 u32].
// Also accumulates input-scale histogram (idxs[1..17) tiles disjointly).
template <int TP, bool WPOOL>
__global__ __launch_bounds__(256) void packN_kernel(
    const u32* __restrict__ pin, const float* __restrict__ cb,
    const u64* __restrict__ packed, char* __restrict__ a_next,
    u32* __restrict__ pout, int* __restrict__ hist) {
  constexpr int OFF = (TP == 1024) ? 32768 : 49152;  // scale-2 / scale-4 idx
  constexpr int TILES = TP / 16;
  constexpr int TO = TP / 2;
  __shared__ float rows[18][516];
  __shared__ int idxs[18];
  const int tid = threadIdx.x;
  const int blk = blockIdx.x;  // 16 n x TILES
  const int n = blk / TILES;
  const int o0 = (blk % TILES) * 8;  // output tau base
  const int s0 = o0 * 2;             // input sigma base
  if (tid < 18) {
    const int sig = iclamp(s0 - 1 + tid, 0, TP - 1);
    const int id = (int)(packed[OFF + (size_t)n * TP + sig] & 0xffffffffull);
    idxs[tid] = id;
    if (tid >= 1 && tid < 17) atomicAdd(&hist[id], 1);  // disjoint exact cover
  }
  __syncthreads();
  for (int j = 0; j < 18; ++j) {
    const int c = tid * 2;
    const float* src = cb + (size_t)idxs[j] * CDIM + c;
    rows[j][c] = src[0];
    rows[j][c + 1] = src[1];
  }
  __syncthreads();

  const int cg = tid >> 1, half = tid & 1;
  const int c0 = cg * 4;
  f32x4 inv[8];
#pragma unroll
  for (int l = 0; l < 8; ++l) {
    i32x2 v = *(const i32x2*)(pin + (size_t)n * (TP * 256) +
                              (size_t)(s0 + half * 8 + l) * 256 + (c0 >> 1));
    inv[l][0] = bflo((u32)v[0]);
    inv[l][1] = bfhi((u32)v[0]);
    inv[l][2] = bflo((u32)v[1]);
    inv[l][3] = bfhi((u32)v[1]);
  }

  float pv[4][4];
#pragma unroll
  for (int q = 0; q < 4; ++q) {
    const int e = half * 8 + 2 * q;
    const int sa = e + 1, sb = e + 2;
    f32x4 Rm = *(const f32x4*)&rows[sa - 1][c0];
    f32x4 Rc = *(const f32x4*)&rows[sa][c0];
    f32x4 Rp = *(const f32x4*)&rows[sb][c0];
    f32x4 Rpp = *(const f32x4*)&rows[sb + 1][c0];
    f32x4 ua = 0.125f * (Rm + Rp) + 0.75f * Rc;
    f32x4 ub = 0.125f * (Rc + Rpp) + 0.75f * Rp;
#pragma unroll
    for (int j = 0; j < 4; ++j)
      pv[j][q] = ((inv[2 * q][j] - ua[j]) + (inv[2 * q + 1][j] - ub[j])) * 0.5f;
  }

  const int kc = c0 >> 6, kbyte = (c0 & 63) * 2;
#pragma unroll
  for (int q = 0; q < 4; ++q) {
    const int tau = o0 + half * 4 + q;
    i32x2 o = {(int)pack2ch(pv[0][q], pv[1][q]),
               (int)pack2ch(pv[2][q], pv[3][q])};
    if constexpr (WPOOL) {
      *(i32x2*)(pout + (size_t)n * (TO * 256) + (size_t)tau * 256 +
                (c0 >> 1)) = o;
    }
    const int m = n * TO + tau;
    *(i32x2*)(a_next + (((size_t)((m >> 7) * 8 + kc)) << 14) +
              tile_addr(m & 127, kbyte)) = o;
  }
}

// ---------------------------------------------------------------------------
// final: full-res pass: 4 per-stage losses + f_hat. No LDS staging; each
// thread processes TWO independent t-quads (2x MLP). Grid 2048.
__global__ __launch_bounds__(256) void final_kernel(
    const float* __restrict__ x, float* __restrict__ out,
    const float* __restrict__ cb, const u64* __restrict__ packed,
    float* __restrict__ lossPart) {
  const int tid = threadIdx.x;
  const int blk = blockIdx.x;  // [n:16][t32:64][ch:2]
  const int ch = blk & 1;
  const int t0 = ((blk >> 1) & 63) * 32;
  const int n = blk >> 7;
  const int cg = tid >> 2, qt = tid & 3;
  const int c0 = ch * 256 + cg * 4;
  const int tbA = t0 + qt * 4;
  const int tbB = t0 + 16 + qt * 4;

  const u64* ip1 = packed + (size_t)n * TDIM;
  const u64* ip2 = packed + 32768 + (size_t)n * 1024;
  const u64* ip4 = packed + 49152 + (size_t)n * 512;
  const u64* ip8 = packed + 57344 + (size_t)n * 256;

  // --- gather both tiles' code-row windows (interleaved for MLP) ---
  f32x4 R1A[4], R2A[4], R4A[3], R8A[2];
  f32x4 R1B[4], R2B[4], R4B[3], R8B[2];
#pragma unroll
  for (int k = 0; k < 4; ++k) {
    R1A[k] = *(const f32x4*)(
        cb + (size_t)(u32)(ip1[tbA + k] & 0xffffffffull) * CDIM + c0);
    R1B[k] = *(const f32x4*)(
        cb + (size_t)(u32)(ip1[tbB + k] & 0xffffffffull) * CDIM + c0);
  }
  const int b2A = tbA >> 1, b2B = tbB >> 1;
#pragma unroll
  for (int k = 0; k < 4; ++k) {
    R2A[k] = *(const f32x4*)(
        cb + (size_t)(u32)(ip2[iclamp(b2A - 1 + k, 0, 1023)] & 0xffffffffull) *
                 CDIM + c0);
    R2B[k] = *(const f32x4*)(
        cb + (size_t)(u32)(ip2[iclamp(b2B - 1 + k, 0, 1023)] & 0xffffffffull) *
                 CDIM + c0);
  }
  const int b4A = tbA >> 2, b4B = tbB >> 2;
#pragma unroll
  for (int k = 0; k < 3; ++k) {
    R4A[k] = *(const f32x4*)(
        cb + (size_t)(u32)(ip4[iclamp(b4A - 1 + k, 0, 511)] & 0xffffffffull) *
                 CDIM + c0);
    R4B[k] = *(const f32x4*)(
        cb + (size_t)(u32)(ip4[iclamp(b4B - 1 + k, 0, 511)] & 0xffffffffull) *
                 CDIM + c0);
  }
  const int b8A = (tbA >> 3) - 1 + ((tbA >> 2) & 1);
  const int b8B = (tbB >> 3) - 1 + ((tbB >> 2) & 1);
#pragma unroll
  for (int k = 0; k < 2; ++k) {
    R8A[k] = *(const f32x4*)(
        cb + (size_t)(u32)(ip8[iclamp(b8A + k, 0, 255)] & 0xffffffffull) *
                 CDIM + c0);
    R8B[k] = *(const f32x4*)(
        cb + (size_t)(u32)(ip8[iclamp(b8B + k, 0, 255)] & 0xffffffffull) *
                 CDIM + c0);
  }

  const size_t xbaseA = (size_t)n * (CDIM * TDIM) + (size_t)c0 * TDIM + tbA;
  const size_t xbaseB = xbaseA + 16;
  f32x4 xaA[4], xaB[4], faA[4], faB[4];
#pragma unroll
  for (int j = 0; j < 4; ++j) {
    xaA[j] = *(const f32x4*)(x + xbaseA + (size_t)j * TDIM);
    xaB[j] = *(const f32x4*)(x + xbaseB + (size_t)j * TDIM);
  }

  // per-tt slot/weight tables (tb ≡ 0 mod 4)
  const int s2n[4] = {0, 1, 1, 2};
  const float w2n[4] = {0.75f, 0.25f, 0.75f, 0.25f};
  const int s4n[4] = {0, 0, 1, 1};
  const float w4n[4] = {0.625f, 0.875f, 0.125f, 0.375f};
  const float w8bA = (tbA & 4) ? 0.0625f : 0.5625f;
  const float w8bB = (tbB & 4) ? 0.0625f : 0.5625f;

  float ss1 = 0.f, ss2 = 0.f, ss3 = 0.f, ss4 = 0.f;
#pragma unroll
  for (int tt = 0; tt < 4; ++tt) {
    // tile A
    {
      f32x4 u2 = R2A[s2n[tt]] * (1.f - w2n[tt]) + R2A[s2n[tt] + 1] * w2n[tt];
      f32x4 u4 = R4A[s4n[tt]] * (1.f - w4n[tt]) + R4A[s4n[tt] + 1] * w4n[tt];
      const float w8 = w8bA + tt * 0.125f;
      f32x4 u8 = R8A[0] * (1.f - w8) + R8A[1] * w8;
      f32x4 xv;
#pragma unroll
      for (int j = 0; j < 4; ++j) xv[j] = xaA[j][tt];
      f32x4 r1 = xv - R1A[tt];
      f32x4 r2 = r1 - u2;
      f32x4 r3 = r2 - u4;
      f32x4 r4 = r3 - u8;
#pragma unroll
      for (int j = 0; j < 4; ++j) {
        ss1 += r1[j] * r1[j];
        ss2 += r2[j] * r2[j];
        ss3 += r3[j] * r3[j];
        ss4 += r4[j] * r4[j];
      }
      f32x4 fh = xv - r4;
#pragma unroll
      for (int j = 0; j < 4; ++j) faA[j][tt] = fh[j];
    }
    // tile B
    {
      f32x4 u2 = R2B[s2n[tt]] * (1.f - w2n[tt]) + R2B[s2n[tt] + 1] * w2n[tt];
      f32x4 u4 = R4B[s4n[tt]] * (1.f - w4n[tt]) + R4B[s4n[tt] + 1] * w4n[tt];
      const float w8 = w8bB + tt * 0.125f;
      f32x4 u8 = R8B[0] * (1.f - w8) + R8B[1] * w8;
      f32x4 xv;
#pragma unroll
      for (int j = 0; j < 4; ++j) xv[j] = xaB[j][tt];
      f32x4 r1 = xv - R1B[tt];
      f32x4 r2 = r1 - u2;
      f32x4 r3 = r2 - u4;
      f32x4 r4 = r3 - u8;
#pragma unroll
      for (int j = 0; j < 4; ++j) {
        ss1 += r1[j] * r1[j];
        ss2 += r2[j] * r2[j];
        ss3 += r3[j] * r3[j];
        ss4 += r4[j] * r4[j];
      }
      f32x4 fh = xv - r4;
#pragma unroll
      for (int j = 0; j < 4; ++j) faB[j][tt] = fh[j];
    }
  }
#pragma unroll
  for (int j = 0; j < 4; ++j) {
    *(f32x4*)(out + xbaseA + (size_t)j * TDIM) = faA[j];
    *(f32x4*)(out + xbaseB + (size_t)j * TDIM) = faB[j];
  }

  __shared__ float red2[4][4];
  float sv[4] = {ss1, ss2, ss3, ss4};
  const int w = tid >> 6, lane = tid & 63;
#pragma unroll
  for (int st = 0; st < 4; ++st) {
    float v = sv[st];
#pragma unroll
    for (int off = 32; off; off >>= 1) v += __shfl_down(v, off, 64);
    if (lane == 0) red2[w][st] = v;
  }
  __syncthreads();
  if (tid < 4)
    lossPart[tid * 2048 + blk] =
        red2[0][tid] + red2[1][tid] + red2[2][tid] + red2[3][tid];
}

// ---------------------------------------------------------------------------
// finalize: loss sum + scale-8 histogram (4096 entries, LDS) + perplexity.
__global__ __launch_bounds__(256) void finalize_kernel(
    const float* __restrict__ lossPart, const int* __restrict__ hist,
    const u64* __restrict__ p8, float* __restrict__ outTail) {
  __shared__ float red[4];
  __shared__ int lhist[KCODE];
  const int tid = threadIdx.x;
  for (int k = tid; k < KCODE; k += 256) lhist[k] = 0;
  __syncthreads();
  for (int i = tid; i < 4096; i += 256) {
    const int code = (int)(p8[i] & 0xffffffffull);
    atomicAdd(&lhist[code], 1);
  }
  float s = 0.f;
  for (int i = tid; i < 4 * 2048; i += 256) s += lossPart[i];
#pragma unroll
  for (int off = 32; off; off >>= 1) s += __shfl_down(s, off, 64);
  if ((tid & 63) == 0) red[tid >> 6] = s;
  __syncthreads();
  const float loss =
      (red[0] + red[1] + red[2] + red[3]) * (1.0f / (4.0f * 16777216.0f));
  __syncthreads();
  float e = 0.f;
  for (int k = tid; k < KCODE; k += 256) {
    float p = (float)(hist[k] + lhist[k]) * (1.0f / 61440.0f);
    e += p * logf(p + 1e-7f);
  }
#pragma unroll
  for (int off = 32; off; off >>= 1) e += __shfl_down(e, off, 64);
  if ((tid & 63) == 0) red[tid >> 6] = e;
  __syncthreads();
  if (tid == 0) {
    outTail[0] = loss;
    outTail[1] = expf(-(red[0] + red[1] + red[2] + red[3]));
  }
}

// ---------------------------------------------------------------------------
extern "C" void kernel_launch(void* const* d_in, const int* in_sizes, int n_in,
                              void* d_out, int out_size, void* d_ws,
                              size_t ws_size, hipStream_t stream) {
  const float* x = (const float*)d_in[0];
  const float* cb = (const float*)d_in[1];
  float* out = (float*)d_out;

  char* ws = (char*)d_ws;
  u64* packed = (u64*)ws;                   // 491520 B
  float* csq = (float*)(ws + 491520);       // 4096 B
  int* hist = (int*)(ws + 495616);          // 4096 B
  float* lossPart = (float*)(ws + 499712);  // 32768 B (4 x 2048)
  char* cb_pack = ws + 565248;              // 1 MiB
  char* a2 = ws + (2ull << 20);             // 16 MiB
  char* a4 = ws + (18ull << 20);            // 8 MiB
  char* a8 = ws + (26ull << 20);            // 4 MiB

  u64* p1 = packed;          // 32768 rows (t_s=2048)
  u64* p2 = packed + 32768;  // 16384 rows
  u64* p4 = packed + 49152;  //  8192 rows
  u64* p8 = packed + 57344;  //  4096 rows

  // d_out region reuse: A1 [0,32MB) + poolx [32,48MB) until pack2; then
  // poolb2 [0,16MB) + poolb4 [16,24MB); finally f_hat overwrites all.
  char* a1 = (char*)out;
  u32* poolx = (u32*)out + 8388608;   // [n][1024][256 u32] = 16 MB @ 32MB
  u32* poolb2 = (u32*)out;            // [n][1024][256 u32] = 16 MB
  u32* poolb4 = (u32*)out + 4194304;  // [n][512][256 u32]  =  8 MB

  prep_kernel<<<1536, 256, 0, stream>>>(cb, cb_pack, csq, x, a1, packed, hist,
                                        poolx);
  gemm_argmin_packed<<<128 * 4, 512, 0, stream>>>(a1, cb_pack, csq, p1);
  pack2_kernel<<<2048, 256, 0, stream>>>(poolx, cb, packed, a2, poolb2, hist);
  gemm_argmin_packed<<<64 * 4, 512, 0, stream>>>(a2, cb_pack, csq, p2);
  packN_kernel<1024, true>
      <<<1024, 256, 0, stream>>>(poolb2, cb, packed, a4, poolb4, hist);
  gemm_argmin_packed<<<32 * 4, 512, 0, stream>>>(a4, cb_pack, csq, p4);
  packN_kernel<512, false>
      <<<512, 256, 0, stream>>>(poolb4, cb, packed, a8, nullptr, hist);
  gemm_argmin_packed<<<16 * 4, 512, 0, stream>>>(a8, cb_pack, csq, p8);
  final_kernel<<<2048, 256, 0, stream>>>(x, out, cb, packed, lossPart);
  finalize_kernel<<<1, 256, 0, stream>>>(lossPart, hist, p8, out + FH_ELEMS);
}